// Round 14
// baseline (797.973 us; speedup 1.0000x reference)
//
#include <hip/hip_runtime.h>

// Encoder block: LN1 -> QKV -> per-token head-mix attention -> scramble ->
// WO -> +x,LN1 -> W1+GELU (2 halves) -> W2 accum (+b2,+q2) -> LN2 in-place.
//
// r14 = r13 with W1 moved gemm256<2> -> gemm192<2>; gemm256<2> deleted.
//  Why: r13's top-5 shows W1 on gemm256<2> at 146 us (was <112 in r12 with
//  IDENTICAL source+launch) — co-compilation codegen perturbation from the
//  new gemm192 instantiations (rule #19). Meanwhile gemm192 measured well
//  for WO (~60) and W2 (~83). Consolidate: all non-QKV GEMMs on gemm192;
//  W1 gets grid 64*16=1024 = 4 sequential rounds/CU (proven regime).
//
//  gemm256 (single-phase, r8): QKV only (grid 768, 112 us, MfmaUtil 38%).
//  gemm192 (256x128 tile, r8 single-phase structure): 8 waves (4M x 2N,
//    wave 64x64), BK=64, LDS 96 KiB (A dbuf 2x32K, B dbuf 2x16K).
//    Per K-tile: read 16 frags -> 24 MFMA -> lgkm0 -> barrier -> stage(u+2
//    into current parity, 6 gloads) -> 8 reg-only MFMA -> vmcnt(6) counted
//    -> barrier. Race discipline: reads all consumed before barrier #1 ->
//    staging current-parity legal; vmcnt(6) retires tile u+1, leaves u+2's
//    6 in flight (full-tile lead >> 900cy HBM miss).
//  Epilogues: r12 vectorized (wave-private LDS transpose + wide stores).
//  XCD mapping (all): bm-banded / bn-fastest (A band L2-resident per XCD).
//
// attn_k: LDS rows padded to 65 floats (16-way bank conflict fix, r7).
// wconv_all: all 7 weight conversions in one launch (r7).
// Workspace footprint: 152 MB (d_out doubles as the f32 residual buffer).

typedef __attribute__((ext_vector_type(8))) short s16x8;
typedef __attribute__((ext_vector_type(4))) short s16x4;
typedef __attribute__((ext_vector_type(4))) float f32x4;

__device__ __forceinline__ short f2bf(float x) {
  unsigned u = __builtin_bit_cast(unsigned, x);
  u = (u + 0x7FFFu + ((u >> 16) & 1u)) >> 16;
  return (short)u;
}
__device__ __forceinline__ float bf2f(short s) {
  unsigned u = ((unsigned)(unsigned short)s) << 16;
  return __builtin_bit_cast(float, u);
}

__device__ __forceinline__ void ld_g2l16(const short* g, const short* l) {
  __builtin_amdgcn_global_load_lds(
      (const __attribute__((address_space(1))) void*)g,
      (__attribute__((address_space(3))) void*)l, 16, 0, 0);
}

// Guaranteed-DS accesses: explicit addrspace(3) so codegen emits ds_* ops.
__device__ __forceinline__ s16x8 lds_read8(const short* smem, int off) {
  const __attribute__((address_space(3))) short* p =
      (const __attribute__((address_space(3))) short*)smem;
  return *(const __attribute__((address_space(3))) s16x8*)(p + off);
}
__device__ __forceinline__ void lds_wr_f32(const short* smem, int foff,
                                           float v) {
  __attribute__((address_space(3))) float* p =
      (__attribute__((address_space(3))) float*)smem;
  p[foff] = v;
}
__device__ __forceinline__ float lds_rd_f32(const short* smem, int foff) {
  const __attribute__((address_space(3))) float* p =
      (const __attribute__((address_space(3))) float*)smem;
  return p[foff];
}

// Fast GELU (tanh form via v_exp_f32; |err| ~1e-3 << bf16 noise).
__device__ __forceinline__ float fast_gelu(float v) {
  float y = 0.7978845608f * (v + 0.044715f * v * v * v);
  float ay = fabsf(y);
  float t = __expf(-2.0f * ay);
  float th = (1.0f - t) * __frcp_rn(1.0f + t);
  th = (y >= 0.f) ? th : -th;
  return 0.5f * v * (1.0f + th);
}

#define MFMA16(va, vb, vc) \
  __builtin_amdgcn_mfma_f32_16x16x32_bf16(va, vb, vc, 0, 0, 0)

// Shared vectorized epilogue body (r12). One 16-row chunk of a wave's
// 64-col tile via wave-private LDS transpose (f32 offset `two`, stride 17).
template <int EPI>
__device__ __forceinline__ void epi_chunk(
    const short* smem, int two, int lane, const f32x4* accm /*[4]*/,
    void* __restrict__ outp, const float* __restrict__ bias, int N, int rowb,
    int nb) {
  const int cc16 = lane & 15, hq = lane >> 4;
#pragma unroll
  for (int n = 0; n < 4; ++n)
#pragma unroll
    for (int r = 0; r < 4; ++r)
      lds_wr_f32(smem, two + (n * 16 + cc16) * 17 + hq * 4 + r, accm[n][r]);
  asm volatile("s_waitcnt lgkmcnt(0)" ::: "memory");
  if constexpr (EPI == 0 || EPI == 2) {
    const int grp = lane & 7;
#pragma unroll
    for (int p = 0; p < 2; ++p) {
      const int row = p * 8 + (lane >> 3);
      const int colb = grp * 8;
      s16x8 ov;
#pragma unroll
      for (int i = 0; i < 8; ++i) {
        float v = lds_rd_f32(smem, two + (colb + i) * 17 + row);
        if constexpr (EPI == 2) v = fast_gelu(v + bias[nb + colb + i]);
        ov[i] = f2bf(v);
      }
      *(s16x8*)((short*)outp + (size_t)(rowb + row) * N + nb + colb) = ov;
    }
  } else {
    const int seg = lane & 3;
    const int row = lane >> 2;
#pragma unroll
    for (int k = 0; k < 4; ++k) {
      const int colb = seg * 4 + k * 16;
      float4 v4;
      v4.x = lds_rd_f32(smem, two + (colb + 0) * 17 + row);
      v4.y = lds_rd_f32(smem, two + (colb + 1) * 17 + row);
      v4.z = lds_rd_f32(smem, two + (colb + 2) * 17 + row);
      v4.w = lds_rd_f32(smem, two + (colb + 3) * 17 + row);
      float* gp = (float*)outp + (size_t)(rowb + row) * N + nb + colb;
      if constexpr (EPI == 4) {
        float4 pv = *(const float4*)gp;
        v4.x += pv.x; v4.y += pv.y; v4.z += pv.z; v4.w += pv.w;
        if (bias) {
          v4.x += bias[nb + colb + 0];
          v4.y += bias[nb + colb + 1];
          v4.z += bias[nb + colb + 2];
          v4.w += bias[nb + colb + 3];
        }
      }
      *(float4*)gp = v4;
    }
  }
  asm volatile("s_waitcnt lgkmcnt(0)" ::: "memory");
}

// ---------------------------------------------------------------------------
// gemm256: C[M,N] = A[M,K] @ BT[N,K]^T. M=16384. N,K multiples of 256.
// grid = 64*(N/256), 512 thr, dyn LDS 131072 B.  (r8 single-phase loop)
// Used for QKV only (EPI=0).
// ---------------------------------------------------------------------------
template <int EPI>
__global__ __launch_bounds__(512, 2) void gemm256(
    const short* __restrict__ A, const short* __restrict__ BT,
    void* __restrict__ outp, const float* __restrict__ bias, int N, int K) {
  extern __shared__ __align__(16) short smem[];

  const int t = threadIdx.x;
  const int lane = t & 63, w = t >> 6;
  const int wm = w >> 2, wn = w & 3;  // wave tile: rows wm*128, cols wn*64

  const int nbn = N >> 8;
  const int oi = (int)blockIdx.x;
  const int seq = oi >> 3;
  const int bq = seq / nbn;
  const int bm = (oi & 7) * 8 + bq;
  const int bn = seq - bq * nbn;

  const int l8 = lane >> 3;
  const int lcw = ((lane & 7) ^ l8) * 8;  // swizzled chunk offset (shorts)
  const short* gA = A + (size_t)(bm * 256 + w * 8 + l8) * K + lcw;
  const short* gB = BT + (size_t)(bn * 256 + w * 8 + l8) * K + lcw;
  const int lb = w * 512;

  auto stage = [&](const short* g, int bufo, int h, int kt) {
    const int go = h * 128 * K + kt * 64;
    ld_g2l16(g + go, smem + bufo + h * 8192 + lb);                  // q = 0
    ld_g2l16(g + go + 64 * K, smem + bufo + h * 8192 + 4096 + lb);  // q = 1
  };

  const int fr = lane & 15, fc = lane >> 4;
  const int baseA = (wm * 128 + fr) * 64;
  const int baseB = (wn * 64 + fr) * 64;
  const int sl0 = (fc ^ (fr & 7)) * 8;
  const int sl1 = ((4 + fc) ^ (fr & 7)) * 8;

  f32x4 acc[8][4];
#pragma unroll
  for (int m = 0; m < 8; ++m)
#pragma unroll
    for (int n = 0; n < 4; ++n) acc[m][n] = (f32x4){0.f, 0.f, 0.f, 0.f};

  const int nt = K >> 6;

  stage(gA, 0, 0, 0);
  stage(gA, 0, 1, 0);
  stage(gB, 32768, 0, 0);
  stage(gB, 32768, 1, 0);
  if (nt > 1) {
    stage(gA, 16384, 0, 1);
    stage(gA, 16384, 1, 1);
    stage(gB, 49152, 0, 1);
    stage(gB, 49152, 1, 1);
    asm volatile("s_waitcnt vmcnt(8)" ::: "memory");
  } else {
    asm volatile("s_waitcnt vmcnt(0)" ::: "memory");
  }
  __builtin_amdgcn_s_barrier();
  asm volatile("" ::: "memory");

  for (int u = 0; u < nt; ++u) {
    const bool pf = (u + 2 < nt);
    const int pa = (u & 1) << 14;
    const int pb = 32768 + pa;

    s16x8 a0[4][2], a1[4][2], b0[2][2], b1[2][2];
#pragma unroll
    for (int mi = 0; mi < 4; ++mi) {
      a0[mi][0] = lds_read8(smem, pa + baseA + mi * 1024 + sl0);
      a0[mi][1] = lds_read8(smem, pa + baseA + mi * 1024 + sl1);
    }
#pragma unroll
    for (int ni = 0; ni < 2; ++ni) {
      b0[ni][0] = lds_read8(smem, pb + baseB + ni * 1024 + sl0);
      b0[ni][1] = lds_read8(smem, pb + baseB + ni * 1024 + sl1);
    }
#pragma unroll
    for (int ni = 0; ni < 2; ++ni) {
      b1[ni][0] = lds_read8(smem, pb + baseB + 2048 + ni * 1024 + sl0);
      b1[ni][1] = lds_read8(smem, pb + baseB + 2048 + ni * 1024 + sl1);
    }
#pragma unroll
    for (int mi = 0; mi < 4; ++mi) {
      a1[mi][0] = lds_read8(smem, pa + baseA + 4096 + mi * 1024 + sl0);
      a1[mi][1] = lds_read8(smem, pa + baseA + 4096 + mi * 1024 + sl1);
    }

    __builtin_amdgcn_s_setprio(1);
#pragma unroll
    for (int mi = 0; mi < 4; ++mi)
#pragma unroll
      for (int ni = 0; ni < 2; ++ni) {
        acc[mi][ni] = MFMA16(a0[mi][0], b0[ni][0], acc[mi][ni]);
        acc[mi][ni] = MFMA16(a0[mi][1], b0[ni][1], acc[mi][ni]);
      }
#pragma unroll
    for (int mi = 0; mi < 4; ++mi)
#pragma unroll
      for (int ni = 0; ni < 2; ++ni) {
        acc[mi][2 + ni] = MFMA16(a0[mi][0], b1[ni][0], acc[mi][2 + ni]);
        acc[mi][2 + ni] = MFMA16(a0[mi][1], b1[ni][1], acc[mi][2 + ni]);
      }
#pragma unroll
    for (int mi = 0; mi < 4; ++mi)
#pragma unroll
      for (int ni = 0; ni < 2; ++ni) {
        acc[4 + mi][2 + ni] = MFMA16(a1[mi][0], b1[ni][0], acc[4 + mi][2 + ni]);
        acc[4 + mi][2 + ni] = MFMA16(a1[mi][1], b1[ni][1], acc[4 + mi][2 + ni]);
      }
    __builtin_amdgcn_s_setprio(0);

    asm volatile("s_waitcnt lgkmcnt(0)" ::: "memory");  // free (consumed)
    __builtin_amdgcn_s_barrier();
    asm volatile("" ::: "memory");

    if (pf) {
      stage(gB, pb, 0, u + 2);
      stage(gB, pb, 1, u + 2);
      stage(gA, pa, 0, u + 2);
      stage(gA, pa, 1, u + 2);
    }

    __builtin_amdgcn_s_setprio(1);
#pragma unroll
    for (int mi = 0; mi < 4; ++mi)
#pragma unroll
      for (int ni = 0; ni < 2; ++ni) {
        acc[4 + mi][ni] = MFMA16(a1[mi][0], b0[ni][0], acc[4 + mi][ni]);
        acc[4 + mi][ni] = MFMA16(a1[mi][1], b0[ni][1], acc[4 + mi][ni]);
      }
    __builtin_amdgcn_s_setprio(0);

    if (pf) {
      asm volatile("s_waitcnt vmcnt(8)" ::: "memory");
    } else {
      asm volatile("s_waitcnt vmcnt(0)" ::: "memory");
    }
    __builtin_amdgcn_s_barrier();
    asm volatile("" ::: "memory");
  }

  const int two = w * 1088;  // f32 offset of wave epilogue region
  const int mb = bm * 256 + wm * 128;
  const int nb = bn * 256 + wn * 64;
#pragma unroll
  for (int m = 0; m < 8; ++m)
    epi_chunk<EPI>(smem, two, lane, acc[m], outp, bias, N, mb + m * 16, nb);
}

// ---------------------------------------------------------------------------
// gemm192: C[M,N] = A[M,K] @ BT[N,K]^T, tile 256x128 (r8 single-phase).
// 8 waves (4M x 2N, wave 64x64), BK=64, LDS 96 KiB:
//   A0 @0 (16384 shorts), A1 @16384, B0 @32768 (8192), B1 @40960.
// Per K-tile: read 16 frags -> 24 MFMA -> lgkm0 -> barrier -> stage(u+2
// into current parity, 6 gloads) -> 8 reg-only MFMA -> vmcnt(6) -> barrier.
// grid = 64*(N/128), 512 thr, dyn LDS 98304 B.
// ---------------------------------------------------------------------------
template <int EPI>
__global__ __launch_bounds__(512, 2) void gemm192(
    const short* __restrict__ A, const short* __restrict__ BT,
    void* __restrict__ outp, const float* __restrict__ bias, int N, int K) {
  extern __shared__ __align__(16) short smem[];

  const int t = threadIdx.x;
  const int lane = t & 63, w = t >> 6;
  const int wm = w >> 1, wn = w & 1;  // wave tile: rows wm*64, cols wn*64

  // bm-banded / bn-fastest XCD mapping; nbm = 64, nbn = N/128.
  const int nbn = N >> 7;
  const int oi = (int)blockIdx.x;
  const int seq = oi >> 3;
  const int bq = seq / nbn;
  const int bm = (oi & 7) * 8 + bq;
  const int bn = seq - bq * nbn;

  const int l8 = lane >> 3;
  const int lcw = ((lane & 7) ^ l8) * 8;  // swizzled chunk offset (shorts)
  const short* gA = A + (size_t)(bm * 256 + w * 8 + l8) * K + lcw;
  const short* gB = BT + (size_t)(bn * 128 + w * 8 + l8) * K + lcw;
  const int lb = w * 512;

  auto stageA = [&](int bufo, int kt) {  // full 256-row A tile: 4 gloads
    const int k64 = kt * 64;
    ld_g2l16(gA + k64, smem + bufo + lb);
    ld_g2l16(gA + 64 * K + k64, smem + bufo + 4096 + lb);
    ld_g2l16(gA + 128 * K + k64, smem + bufo + 8192 + lb);
    ld_g2l16(gA + 192 * K + k64, smem + bufo + 12288 + lb);
  };
  auto stageB = [&](int bufo, int kt) {  // 128-row B tile: 2 gloads
    const int k64 = kt * 64;
    ld_g2l16(gB + k64, smem + bufo + lb);
    ld_g2l16(gB + 64 * K + k64, smem + bufo + 4096 + lb);
  };

  const int fr = lane & 15, fc = lane >> 4;
  const int baseA = (wm * 64 + fr) * 64;
  const int baseB = (wn * 64 + fr) * 64;
  const int sl0 = (fc ^ (fr & 7)) * 8;
  const int sl1 = ((4 + fc) ^ (fr & 7)) * 8;

  f32x4 acc[4][4];
#pragma unroll
  for (int m = 0; m < 4; ++m)
#pragma unroll
    for (int n = 0; n < 4; ++n) acc[m][n] = (f32x4){0.f, 0.f, 0.f, 0.f};

  const int nt = K >> 6;

  // Prologue: tile0 -> parity 0, tile1 -> parity 1 (12 loads); wait to 6.
  stageA(0, 0);
  stageB(32768, 0);
  stageA(16384, 1);
  stageB(40960, 1);
  asm volatile("s_waitcnt vmcnt(6)" ::: "memory");  // tile0 landed
  __builtin_amdgcn_s_barrier();
  asm volatile("" ::: "memory");

  for (int u = 0; u < nt; ++u) {
    const bool pf = (u + 2 < nt);
    const int pa = (u & 1) << 14;           // 0 / 16384
    const int pb = 32768 + ((u & 1) << 13); // 32768 / 40960

    s16x8 a[4][2], b[4][2];
#pragma unroll
    for (int mi = 0; mi < 4; ++mi) {
      a[mi][0] = lds_read8(smem, pa + baseA + mi * 1024 + sl0);
      a[mi][1] = lds_read8(smem, pa + baseA + mi * 1024 + sl1);
    }
#pragma unroll
    for (int ni = 0; ni < 4; ++ni) {
      b[ni][0] = lds_read8(smem, pb + baseB + ni * 1024 + sl0);
      b[ni][1] = lds_read8(smem, pb + baseB + ni * 1024 + sl1);
    }

    // Batch 1: mi = 0..2 (24 MFMA) — consumes a[0..2], all b.
    __builtin_amdgcn_s_setprio(1);
#pragma unroll
    for (int mi = 0; mi < 3; ++mi)
#pragma unroll
      for (int ni = 0; ni < 4; ++ni) {
        acc[mi][ni] = MFMA16(a[mi][0], b[ni][0], acc[mi][ni]);
        acc[mi][ni] = MFMA16(a[mi][1], b[ni][1], acc[mi][ni]);
      }
    __builtin_amdgcn_s_setprio(0);

    asm volatile("s_waitcnt lgkmcnt(0)" ::: "memory");  // all reads retired
    __builtin_amdgcn_s_barrier();
    asm volatile("" ::: "memory");

    if (pf) {
      stageA(pa, u + 2);
      stageB(pb, u + 2);
    }

    // Batch 2: mi = 3 (8 MFMA, register-only) overlaps the staging loads.
    __builtin_amdgcn_s_setprio(1);
#pragma unroll
    for (int ni = 0; ni < 4; ++ni) {
      acc[3][ni] = MFMA16(a[3][0], b[ni][0], acc[3][ni]);
      acc[3][ni] = MFMA16(a[3][1], b[ni][1], acc[3][ni]);
    }
    __builtin_amdgcn_s_setprio(0);

    if (pf) {
      asm volatile("s_waitcnt vmcnt(6)" ::: "memory");  // tile u+1 resident
    } else {
      asm volatile("s_waitcnt vmcnt(0)" ::: "memory");  // tail drain
    }
    __builtin_amdgcn_s_barrier();
    asm volatile("" ::: "memory");
  }

  const int two = w * 1088;
  const int mb = bm * 256 + wm * 64;
  const int nb = bn * 128 + wn * 64;
#pragma unroll
  for (int m = 0; m < 4; ++m)
    epi_chunk<EPI>(smem, two, lane, acc[m], outp, bias, N, mb + m * 16, nb);
}

// ---------------------------------------------------------------------------
// Row LayerNorm over D=1024. Optional fp32 `add` (residual). Writes fp32
// and/or bf16. One block (256 thr) per row. Safe in-place (outf == in).
// ---------------------------------------------------------------------------
__global__ __launch_bounds__(256) void ln_k(
    const float* __restrict__ in, const float* __restrict__ add,
    const float* __restrict__ g, const float* __restrict__ b,
    float* __restrict__ outf, short* __restrict__ outb) {
  const int row = blockIdx.x;
  const size_t off = (size_t)row * 1024;
  const int t = threadIdx.x;
  float4 v = ((const float4*)(in + off))[t];
  if (add) {
    float4 w = ((const float4*)(add + off))[t];
    v.x += w.x; v.y += w.y; v.z += w.z; v.w += w.w;
  }
  float s = v.x + v.y + v.z + v.w;
  float ss = v.x * v.x + v.y * v.y + v.z * v.z + v.w * v.w;
#pragma unroll
  for (int o = 32; o > 0; o >>= 1) {
    s += __shfl_xor(s, o, 64);
    ss += __shfl_xor(ss, o, 64);
  }
  __shared__ float ps[4], pss[4];
  const int lane = t & 63, wave = t >> 6;
  if (lane == 0) { ps[wave] = s; pss[wave] = ss; }
  __syncthreads();
  s = ps[0] + ps[1] + ps[2] + ps[3];
  ss = pss[0] + pss[1] + pss[2] + pss[3];
  const float mean = s * (1.0f / 1024.0f);
  const float var = ss * (1.0f / 1024.0f) - mean * mean;
  const float rstd = rsqrtf(var + 1e-6f);
  const float4 gv = ((const float4*)g)[t];
  const float4 bv = ((const float4*)b)[t];
  float4 o4;
  o4.x = (v.x - mean) * rstd * gv.x + bv.x;
  o4.y = (v.y - mean) * rstd * gv.y + bv.y;
  o4.z = (v.z - mean) * rstd * gv.z + bv.z;
  o4.w = (v.w - mean) * rstd * gv.w + bv.w;
  if (outf) ((float4*)(outf + off))[t] = o4;
  if (outb) {
    s16x4 ob;
    ob[0] = f2bf(o4.x); ob[1] = f2bf(o4.y);
    ob[2] = f2bf(o4.z); ob[3] = f2bf(o4.w);
    *(s16x4*)(outb + off + t * 4) = ob;
  }
}

// ---------------------------------------------------------------------------
// Fused weight convert+transpose: all 7 weight matrices in ONE launch.
// ---------------------------------------------------------------------------
__device__ __forceinline__ void wconv_tile(const float* __restrict__ W,
                                           short* __restrict__ WT, int K,
                                           int N, int n0, int k0,
                                           float (*tile)[33], int c, int r) {
#pragma unroll
  for (int rr = r; rr < 32; rr += 8)
    tile[rr][c] = W[(size_t)(k0 + rr) * N + n0 + c];
  __syncthreads();
#pragma unroll
  for (int rr = r; rr < 32; rr += 8)
    WT[(size_t)(n0 + rr) * K + k0 + c] = f2bf(tile[c][rr]);
}

__global__ __launch_bounds__(256) void wconv_all(
    const float* __restrict__ wq, const float* __restrict__ wk,
    const float* __restrict__ wv, const float* __restrict__ wo,
    const float* __restrict__ w1, const float* __restrict__ w2,
    short* __restrict__ WQKVT, short* __restrict__ WOT,
    short* __restrict__ W1T, short* __restrict__ W2aT,
    short* __restrict__ W2bT) {
  __shared__ float tile[32][33];
  const int t = threadIdx.x;
  const int c = t & 31, r = t >> 5;
  const int i = blockIdx.x;
  if (i < 4096) {  // wq/wk/wv/wo: 1024x1024, 32x32 tiles each
    const int seg = i >> 10, j = i & 1023;
    const int n0 = (j & 31) * 32, k0 = (j >> 5) * 32;
    const float* src = (seg == 0) ? wq : (seg == 1) ? wk : (seg == 2) ? wv : wo;
    short* dst = (seg == 3) ? WOT : WQKVT + (size_t)seg * 1024 * 1024;
    wconv_tile(src, dst, 1024, 1024, n0, k0, tile, c, r);
  } else if (i < 8192) {  // w1: K=1024, N=4096
    const int j = i - 4096;
    const int n0 = (j & 127) * 32, k0 = (j >> 7) * 32;
    wconv_tile(w1, W1T, 1024, 4096, n0, k0, tile, c, r);
  } else if (i < 10240) {  // w2 rows 0-2047 -> W2aT
    const int j = i - 8192;
    const int n0 = (j & 31) * 32, k0 = (j >> 5) * 32;
    wconv_tile(w2, W2aT, 2048, 1024, n0, k0, tile, c, r);
  } else {  // w2 rows 2048-4095 -> W2bT
    const int j = i - 10240;
    const int n0 = (j & 31) * 32, k0 = (j >> 5) * 32;
    wconv_tile(w2 + (size_t)2048 * 1024, W2bT, 2048, 1024, n0, k0, tile, c, r);
  }
}

// ---------------------------------------------------------------------------
// Per-token head-mixing attention + faithful-reshape scramble.
// LDS rows padded: stride 65 (= 1 mod 32). Ps stride 17.
// ---------------------------------------------------------------------------
__global__ __launch_bounds__(256) void attn_k(const short* __restrict__ qkv,
                                              short* __restrict__ omix) {
  __shared__ float Qs[4][16][65];
  __shared__ float Ks[4][16][65];
  __shared__ float Vs[4][16][65];
  __shared__ float Ps[4][16][17];
  const int lane = threadIdx.x & 63;
  const int wave = threadIdx.x >> 6;
  const int tok = blockIdx.x * 4 + wave;
  const short* base = qkv + (size_t)tok * 3072;

#pragma unroll
  for (int half = 0; half < 2; half++) {
    const int e = half * 512 + lane * 8;
    const int h = e >> 6, d = e & 63;
    s16x8 rq = *(const s16x8*)(base + e);
    s16x8 rk = *(const s16x8*)(base + 1024 + e);
    s16x8 rv = *(const s16x8*)(base + 2048 + e);
#pragma unroll
    for (int j = 0; j < 8; j++) {
      Qs[wave][h][d + j] = bf2f(rq[j]);
      Ks[wave][h][d + j] = bf2f(rk[j]);
      Vs[wave][h][d + j] = bf2f(rv[j]);
    }
  }
  __syncthreads();

  const int h = lane & 15;
  const int g0 = (lane >> 4) * 4;
  float sc[4] = {0.f, 0.f, 0.f, 0.f};
  for (int d = 0; d < 64; d++) {
    const float qv = Qs[wave][h][d];
#pragma unroll
    for (int i = 0; i < 4; i++) sc[i] += qv * Ks[wave][g0 + i][d];
  }
#pragma unroll
  for (int i = 0; i < 4; i++) sc[i] *= 0.125f;
  float m = fmaxf(fmaxf(sc[0], sc[1]), fmaxf(sc[2], sc[3]));
  m = fmaxf(m, __shfl_xor(m, 16, 64));
  m = fmaxf(m, __shfl_xor(m, 32, 64));
  float e[4], sum = 0.f;
#pragma unroll
  for (int i = 0; i < 4; i++) { e[i] = __expf(sc[i] - m); sum += e[i]; }
  sum += __shfl_xor(sum, 16, 64);
  sum += __shfl_xor(sum, 32, 64);
  const float inv = __frcp_rn(sum);
#pragma unroll
  for (int i = 0; i < 4; i++) Ps[wave][h][g0 + i] = e[i] * inv;
  __syncthreads();

  const int d0 = (lane >> 4) * 16;
  float o[16];
#pragma unroll
  for (int dd = 0; dd < 16; dd++) o[dd] = 0.f;
  for (int gg = 0; gg < 16; gg++) {
    const float pv = Ps[wave][h][gg];
#pragma unroll
    for (int dd = 0; dd < 16; dd++) o[dd] += pv * Vs[wave][gg][d0 + dd];
  }

  const int b = tok >> 12, t = tok & 4095;
  const size_t dst =
      ((size_t)(b * 4096 + h * 256 + (t >> 4))) * 1024 + (t & 15) * 64 + d0;
  s16x8 w0, w1;
#pragma unroll
  for (int j = 0; j < 8; j++) { w0[j] = f2bf(o[j]); w1[j] = f2bf(o[8 + j]); }
  *(s16x8*)(omix + dst) = w0;
  *(s16x8*)(omix + dst + 8) = w1;
}

// ---------------------------------------------------------------------------
extern "C" void kernel_launch(void* const* d_in, const int* in_sizes, int n_in,
                              void* d_out, int out_size, void* d_ws,
                              size_t ws_size, hipStream_t stream) {
  const float* x    = (const float*)d_in[0];
  const float* wq   = (const float*)d_in[1];
  const float* wk   = (const float*)d_in[2];
  const float* wv   = (const float*)d_in[3];
  const float* wo   = (const float*)d_in[4];
  const float* ln1g = (const float*)d_in[5];
  const float* ln1b = (const float*)d_in[6];
  const float* w1   = (const float*)d_in[7];
  const float* b1   = (const float*)d_in[8];
  const float* w2   = (const float*)d_in[9];
  const float* b2   = (const float*)d_in[10];
  const float* ln2g = (const float*)d_in[11];
  const float* ln2b = (const float*)d_in[12];
  float* out = (float*)d_out;  // [16384,1024] f32; doubles as o2/q2 buffer

  char* ws = (char*)d_ws;
  const size_t MB = 1024ull * 1024ull;
  const size_t NEEDED = 152 * MB;
  if (ws_size < NEEDED) return;  // fail-numeric instead of page-fault

  short* QKV  = (short*)(ws + 0);        // phase1 [16384,3072] bf16
  short* Q2B  = (short*)(ws + 0);        // phase2 [16384,1024] bf16
  short* Hbuf = (short*)(ws + 32 * MB);  // phase2 [16384,2048] bf16
  short* X1 = (short*)(ws + 96 * MB);    // x1, then o_mixed bf16
  short* WQKVT = (short*)(ws + 128 * MB);
  short* WOT   = (short*)(ws + 134 * MB);
  short* W1T   = (short*)(ws + 136 * MB);
  short* W2aT  = (short*)(ws + 144 * MB);
  short* W2bT  = (short*)(ws + 148 * MB);

  const dim3 B256(256);
  const dim3 B512(512);
  const unsigned LDS256 = 131072;  // gemm256
  const unsigned LDS192 = 98304;   // gemm192

  static bool attr_done = false;
  if (!attr_done) {
    attr_done = true;
    void (*k0)(const short*, const short*, void*, const float*, int, int) =
        gemm256<0>;
    (void)hipFuncSetAttribute((const void*)k0,
        hipFuncAttributeMaxDynamicSharedMemorySize, (int)LDS256);
    void (*g1)(const short*, const short*, void*, const float*, int, int) =
        gemm192<1>;
    void (*g2)(const short*, const short*, void*, const float*, int, int) =
        gemm192<2>;
    void (*g4)(const short*, const short*, void*, const float*, int, int) =
        gemm192<4>;
    (void)hipFuncSetAttribute((const void*)g1,
        hipFuncAttributeMaxDynamicSharedMemorySize, (int)LDS192);
    (void)hipFuncSetAttribute((const void*)g2,
        hipFuncAttributeMaxDynamicSharedMemorySize, (int)LDS192);
    (void)hipFuncSetAttribute((const void*)g4,
        hipFuncAttributeMaxDynamicSharedMemorySize, (int)LDS192);
  }

  // All weight conversions in one launch.
  wconv_all<<<dim3(12288), B256, 0, stream>>>(wq, wk, wv, wo, w1, w2, WQKVT,
                                              WOT, W1T, W2aT, W2bT);

  // x1 = LN1(x) -> bf16
  ln_k<<<16384, B256, 0, stream>>>(x, nullptr, ln1g, ln1b, nullptr, X1);

  // QKV = x1 @ [wq|wk|wv]   (gemm256, grid 768)
  gemm256<0><<<dim3(768), B512, LDS256, stream>>>(X1, WQKVT, QKV, nullptr,
                                                  3072, 1024);

  // attention + scramble -> o_mixed (reuses X1 region)
  attn_k<<<4096, B256, 0, stream>>>(QKV, X1);

  // o2 = o_mixed @ wo -> f32 into d_out   (gemm192: grid 512)
  gemm192<1><<<dim3(512), B512, LDS192, stream>>>(X1, WOT, out, nullptr,
                                                  1024, 1024);

  // q2 = LN1(o2 + x): f32 in-place in d_out, bf16 copy in Q2B
  ln_k<<<16384, B256, 0, stream>>>(out, x, ln1g, ln1b, out, Q2B);

  // FFN half A  (W1: gemm192 grid 1024 = 4 rounds/CU; W2: gemm192 grid 512)
  gemm192<2><<<dim3(1024), B512, LDS192, stream>>>(Q2B, W1T, Hbuf, b1,
                                                   2048, 1024);
  gemm192<4><<<dim3(512), B512, LDS192, stream>>>(Hbuf, W2aT, out, nullptr,
                                                  1024, 2048);

  // FFN half B
  gemm192<2><<<dim3(1024), B512, LDS192, stream>>>(Q2B, W1T + 2048 * 1024,
                                                   Hbuf, b1 + 2048, 2048,
                                                   1024);
  gemm192<4><<<dim3(512), B512, LDS192, stream>>>(Hbuf, W2bT, out, b2,
                                                  1024, 2048);

  // out = LN2(y) in-place
  ln_k<<<16384, B256, 0, stream>>>(out, nullptr, ln2g, ln2b, out, nullptr);
}

// Round 15
// 777.182 us; speedup vs baseline: 1.0268x; 1.0268x over previous
//
#include <hip/hip_runtime.h>

// Encoder block: LN1 -> QKV -> per-token head-mix attention -> scramble ->
// WO -> +x,LN1 -> W1+GELU (2 halves) -> W2 accum (+b2,+q2) -> LN2 in-place.
//
// r15 = r12 restored byte-for-byte (measured best: 767.4 us).
//  r13/r14 established that this module is COMPILE-COUPLED (rule #19):
//  changing one gemm template instantiation perturbs the codegen of
//  sibling instantiations by +-30-60 us (r13: untouched gemm256<2> W1
//  112->146; r14: previously-good gemm192<1>/<4> regressed when <2> was
//  added). The only trustworthy configuration is one measured end-to-end.
//
//  gemm256 (single-phase, r8): 256x256 / BK=64 / 8 waves / 128 KiB LDS.
//    QKV (grid 768) + W1 halves (grid 512; >=2 rounds/CU regime).
//  gemm128 (ring-3, r9): 128x256 / BK=32 / 8 waves / 72 KiB LDS (3 slots),
//    ONE barrier/K-tile, (512,4) VGPR budget 128. WO + W2 halves (grid 512,
//    2 blocks/CU; N=1024 on gemm256 would be the measured-bad 1-round).
//  Epilogues: vectorized (per-wave LDS transpose, 64 cols x 17-f32 stride;
//  wide s16x8/float4 stores; EPI=4 float4 prev-reads).
//  XCD mapping (both): bm-banded / bn-fastest (A band L2-resident per XCD).
//
// attn_k: LDS rows padded to 65 floats (16-way bank conflict fix, r7).
// wconv_all: all 7 weight conversions in one launch (r7).
// Workspace footprint: 152 MB (d_out doubles as the f32 residual buffer).

typedef __attribute__((ext_vector_type(8))) short s16x8;
typedef __attribute__((ext_vector_type(4))) short s16x4;
typedef __attribute__((ext_vector_type(4))) float f32x4;

__device__ __forceinline__ short f2bf(float x) {
  unsigned u = __builtin_bit_cast(unsigned, x);
  u = (u + 0x7FFFu + ((u >> 16) & 1u)) >> 16;
  return (short)u;
}
__device__ __forceinline__ float bf2f(short s) {
  unsigned u = ((unsigned)(unsigned short)s) << 16;
  return __builtin_bit_cast(float, u);
}

__device__ __forceinline__ void ld_g2l16(const short* g, const short* l) {
  __builtin_amdgcn_global_load_lds(
      (const __attribute__((address_space(1))) void*)g,
      (__attribute__((address_space(3))) void*)l, 16, 0, 0);
}

// Guaranteed-DS accesses: explicit addrspace(3) so codegen emits ds_* ops.
__device__ __forceinline__ s16x8 lds_read8(const short* smem, int off) {
  const __attribute__((address_space(3))) short* p =
      (const __attribute__((address_space(3))) short*)smem;
  return *(const __attribute__((address_space(3))) s16x8*)(p + off);
}
__device__ __forceinline__ void lds_wr_f32(const short* smem, int foff,
                                           float v) {
  __attribute__((address_space(3))) float* p =
      (__attribute__((address_space(3))) float*)smem;
  p[foff] = v;
}
__device__ __forceinline__ float lds_rd_f32(const short* smem, int foff) {
  const __attribute__((address_space(3))) float* p =
      (const __attribute__((address_space(3))) float*)smem;
  return p[foff];
}

// Fast GELU (tanh form via v_exp_f32; |err| ~1e-3 << bf16 noise).
__device__ __forceinline__ float fast_gelu(float v) {
  float y = 0.7978845608f * (v + 0.044715f * v * v * v);
  float ay = fabsf(y);
  float t = __expf(-2.0f * ay);
  float th = (1.0f - t) * __frcp_rn(1.0f + t);
  th = (y >= 0.f) ? th : -th;
  return 0.5f * v * (1.0f + th);
}

#define MFMA16(va, vb, vc) \
  __builtin_amdgcn_mfma_f32_16x16x32_bf16(va, vb, vc, 0, 0, 0)

// Shared vectorized epilogue body. Writes one 16-row chunk of a wave's
// 64-col tile. t-region: wave-private, f32 offset `two`, stride 17.
// EPI: 0 bf16; 1 f32; 2 +bias,GELU,bf16; 4 f32 accum (+bias).
template <int EPI>
__device__ __forceinline__ void epi_chunk(
    const short* smem, int two, int lane, const f32x4* accm /*[4]*/,
    void* __restrict__ outp, const float* __restrict__ bias, int N, int rowb,
    int nb) {
  const int cc16 = lane & 15, hq = lane >> 4;
#pragma unroll
  for (int n = 0; n < 4; ++n)
#pragma unroll
    for (int r = 0; r < 4; ++r)
      lds_wr_f32(smem, two + (n * 16 + cc16) * 17 + hq * 4 + r, accm[n][r]);
  asm volatile("s_waitcnt lgkmcnt(0)" ::: "memory");
  if constexpr (EPI == 0 || EPI == 2) {
    const int grp = lane & 7;
#pragma unroll
    for (int p = 0; p < 2; ++p) {
      const int row = p * 8 + (lane >> 3);
      const int colb = grp * 8;
      s16x8 ov;
#pragma unroll
      for (int i = 0; i < 8; ++i) {
        float v = lds_rd_f32(smem, two + (colb + i) * 17 + row);
        if constexpr (EPI == 2) v = fast_gelu(v + bias[nb + colb + i]);
        ov[i] = f2bf(v);
      }
      *(s16x8*)((short*)outp + (size_t)(rowb + row) * N + nb + colb) = ov;
    }
  } else {
    const int seg = lane & 3;
    const int row = lane >> 2;
#pragma unroll
    for (int k = 0; k < 4; ++k) {
      const int colb = seg * 4 + k * 16;
      float4 v4;
      v4.x = lds_rd_f32(smem, two + (colb + 0) * 17 + row);
      v4.y = lds_rd_f32(smem, two + (colb + 1) * 17 + row);
      v4.z = lds_rd_f32(smem, two + (colb + 2) * 17 + row);
      v4.w = lds_rd_f32(smem, two + (colb + 3) * 17 + row);
      float* gp = (float*)outp + (size_t)(rowb + row) * N + nb + colb;
      if constexpr (EPI == 4) {
        float4 pv = *(const float4*)gp;
        v4.x += pv.x; v4.y += pv.y; v4.z += pv.z; v4.w += pv.w;
        if (bias) {
          v4.x += bias[nb + colb + 0];
          v4.y += bias[nb + colb + 1];
          v4.z += bias[nb + colb + 2];
          v4.w += bias[nb + colb + 3];
        }
      }
      *(float4*)gp = v4;
    }
  }
  asm volatile("s_waitcnt lgkmcnt(0)" ::: "memory");
}

// ---------------------------------------------------------------------------
// gemm256: C[M,N] = A[M,K] @ BT[N,K]^T. M=16384. N,K multiples of 256.
// grid = 64*(N/256), 512 thr, dyn LDS 131072 B.  (r8 single-phase loop)
// ---------------------------------------------------------------------------
template <int EPI>
__global__ __launch_bounds__(512, 2) void gemm256(
    const short* __restrict__ A, const short* __restrict__ BT,
    void* __restrict__ outp, const float* __restrict__ bias, int N, int K) {
  extern __shared__ __align__(16) short smem[];

  const int t = threadIdx.x;
  const int lane = t & 63, w = t >> 6;
  const int wm = w >> 2, wn = w & 3;  // wave tile: rows wm*128, cols wn*64

  const int nbn = N >> 8;
  const int oi = (int)blockIdx.x;
  const int seq = oi >> 3;
  const int bq = seq / nbn;
  const int bm = (oi & 7) * 8 + bq;
  const int bn = seq - bq * nbn;

  const int l8 = lane >> 3;
  const int lcw = ((lane & 7) ^ l8) * 8;  // swizzled chunk offset (shorts)
  const short* gA = A + (size_t)(bm * 256 + w * 8 + l8) * K + lcw;
  const short* gB = BT + (size_t)(bn * 256 + w * 8 + l8) * K + lcw;
  const int lb = w * 512;

  auto stage = [&](const short* g, int bufo, int h, int kt) {
    const int go = h * 128 * K + kt * 64;
    ld_g2l16(g + go, smem + bufo + h * 8192 + lb);                  // q = 0
    ld_g2l16(g + go + 64 * K, smem + bufo + h * 8192 + 4096 + lb);  // q = 1
  };

  const int fr = lane & 15, fc = lane >> 4;
  const int baseA = (wm * 128 + fr) * 64;
  const int baseB = (wn * 64 + fr) * 64;
  const int sl0 = (fc ^ (fr & 7)) * 8;
  const int sl1 = ((4 + fc) ^ (fr & 7)) * 8;

  f32x4 acc[8][4];
#pragma unroll
  for (int m = 0; m < 8; ++m)
#pragma unroll
    for (int n = 0; n < 4; ++n) acc[m][n] = (f32x4){0.f, 0.f, 0.f, 0.f};

  const int nt = K >> 6;

  stage(gA, 0, 0, 0);
  stage(gA, 0, 1, 0);
  stage(gB, 32768, 0, 0);
  stage(gB, 32768, 1, 0);
  if (nt > 1) {
    stage(gA, 16384, 0, 1);
    stage(gA, 16384, 1, 1);
    stage(gB, 49152, 0, 1);
    stage(gB, 49152, 1, 1);
    asm volatile("s_waitcnt vmcnt(8)" ::: "memory");
  } else {
    asm volatile("s_waitcnt vmcnt(0)" ::: "memory");
  }
  __builtin_amdgcn_s_barrier();
  asm volatile("" ::: "memory");

  for (int u = 0; u < nt; ++u) {
    const bool pf = (u + 2 < nt);
    const int pa = (u & 1) << 14;
    const int pb = 32768 + pa;

    s16x8 a0[4][2], a1[4][2], b0[2][2], b1[2][2];
#pragma unroll
    for (int mi = 0; mi < 4; ++mi) {
      a0[mi][0] = lds_read8(smem, pa + baseA + mi * 1024 + sl0);
      a0[mi][1] = lds_read8(smem, pa + baseA + mi * 1024 + sl1);
    }
#pragma unroll
    for (int ni = 0; ni < 2; ++ni) {
      b0[ni][0] = lds_read8(smem, pb + baseB + ni * 1024 + sl0);
      b0[ni][1] = lds_read8(smem, pb + baseB + ni * 1024 + sl1);
    }
#pragma unroll
    for (int ni = 0; ni < 2; ++ni) {
      b1[ni][0] = lds_read8(smem, pb + baseB + 2048 + ni * 1024 + sl0);
      b1[ni][1] = lds_read8(smem, pb + baseB + 2048 + ni * 1024 + sl1);
    }
#pragma unroll
    for (int mi = 0; mi < 4; ++mi) {
      a1[mi][0] = lds_read8(smem, pa + baseA + 4096 + mi * 1024 + sl0);
      a1[mi][1] = lds_read8(smem, pa + baseA + 4096 + mi * 1024 + sl1);
    }

    __builtin_amdgcn_s_setprio(1);
#pragma unroll
    for (int mi = 0; mi < 4; ++mi)
#pragma unroll
      for (int ni = 0; ni < 2; ++ni) {
        acc[mi][ni] = MFMA16(a0[mi][0], b0[ni][0], acc[mi][ni]);
        acc[mi][ni] = MFMA16(a0[mi][1], b0[ni][1], acc[mi][ni]);
      }
#pragma unroll
    for (int mi = 0; mi < 4; ++mi)
#pragma unroll
      for (int ni = 0; ni < 2; ++ni) {
        acc[mi][2 + ni] = MFMA16(a0[mi][0], b1[ni][0], acc[mi][2 + ni]);
        acc[mi][2 + ni] = MFMA16(a0[mi][1], b1[ni][1], acc[mi][2 + ni]);
      }
#pragma unroll
    for (int mi = 0; mi < 4; ++mi)
#pragma unroll
      for (int ni = 0; ni < 2; ++ni) {
        acc[4 + mi][2 + ni] = MFMA16(a1[mi][0], b1[ni][0], acc[4 + mi][2 + ni]);
        acc[4 + mi][2 + ni] = MFMA16(a1[mi][1], b1[ni][1], acc[4 + mi][2 + ni]);
      }
    __builtin_amdgcn_s_setprio(0);

    asm volatile("s_waitcnt lgkmcnt(0)" ::: "memory");  // free (consumed)
    __builtin_amdgcn_s_barrier();
    asm volatile("" ::: "memory");

    if (pf) {
      stage(gB, pb, 0, u + 2);
      stage(gB, pb, 1, u + 2);
      stage(gA, pa, 0, u + 2);
      stage(gA, pa, 1, u + 2);
    }

    __builtin_amdgcn_s_setprio(1);
#pragma unroll
    for (int mi = 0; mi < 4; ++mi)
#pragma unroll
      for (int ni = 0; ni < 2; ++ni) {
        acc[4 + mi][ni] = MFMA16(a1[mi][0], b0[ni][0], acc[4 + mi][ni]);
        acc[4 + mi][ni] = MFMA16(a1[mi][1], b0[ni][1], acc[4 + mi][ni]);
      }
    __builtin_amdgcn_s_setprio(0);

    if (pf) {
      asm volatile("s_waitcnt vmcnt(8)" ::: "memory");
    } else {
      asm volatile("s_waitcnt vmcnt(0)" ::: "memory");
    }
    __builtin_amdgcn_s_barrier();
    asm volatile("" ::: "memory");
  }

  // Vectorized epilogue (wave-private LDS transpose; LDS free after loop).
  const int two = w * 1088;  // f32 offset of wave region (4352 B each)
  const int mb = bm * 256 + wm * 128;
  const int nb = bn * 256 + wn * 64;
#pragma unroll
  for (int m = 0; m < 8; ++m)
    epi_chunk<EPI>(smem, two, lane, acc[m], outp, bias, N, mb + m * 16, nb);
}

// ---------------------------------------------------------------------------
// gemm128 RING-3: tile 128x256, BK=32, 8 waves (2Mx4N, wave 64x64).
// LDS = 3 parity slots x 24 KB = 73728 B. ONE barrier + one counted vmcnt
// per K-tile. __launch_bounds__(512,4): 2 blocks/CU. grid = 128*(N/256).
// ---------------------------------------------------------------------------
template <int EPI>
__global__ __launch_bounds__(512, 4) void gemm128(
    const short* __restrict__ A, const short* __restrict__ BT,
    void* __restrict__ outp, const float* __restrict__ bias, int N, int K) {
  extern __shared__ __align__(16) short smem[];

  const int t = threadIdx.x;
  const int lane = t & 63, w = t >> 6;
  const int wm = w >> 2, wn = w & 3;  // wave tile: rows wm*64, cols wn*64

  // bm-banded / bn-fastest XCD mapping; nbm = 128 (M = 16384).
  const int nbn = N >> 8;
  const int oi = (int)blockIdx.x;
  const int seq = oi >> 3;
  const int bq = seq / nbn;
  const int bm = (oi & 7) * 16 + bq;
  const int bn = seq - bq * nbn;

  // Staging: lane -> (row = lane>>2, LDS slot = lane&3); global chunk
  // pre-rotated: c = ((lane&3) - ((lane>>3)&3)) & 3.
  const int lr = lane >> 2;
  const int lc = ((lane & 3) - ((lane >> 3) & 3)) & 3;
  const short* gA = A + (size_t)(bm * 128 + lr) * K + lc * 8;
  const short* gB = BT + (size_t)(bn * 256 + lr) * K + lc * 8;

  auto stageT = [&](int par, int kt) {
    ld_g2l16(gA + (size_t)(w * 16) * K + kt * 32, smem + par + w * 512);
    ld_g2l16(gB + (size_t)(2 * w * 16) * K + kt * 32,
             smem + par + 4096 + 2 * w * 512);
    ld_g2l16(gB + (size_t)((2 * w + 1) * 16) * K + kt * 32,
             smem + par + 4096 + (2 * w + 1) * 512);
  };

  const int fr = lane & 15, fc = lane >> 4;
  const int sl = ((fc + (fr >> 1)) & 3) * 8;
  const int baseA = (wm * 64 + fr) * 32 + sl;
  const int baseB = 4096 + (wn * 64 + fr) * 32 + sl;

  f32x4 acc[4][4];
#pragma unroll
  for (int m = 0; m < 4; ++m)
#pragma unroll
    for (int n = 0; n < 4; ++n) acc[m][n] = (f32x4){0.f, 0.f, 0.f, 0.f};

  const int nt = K >> 5;

  stageT(0, 0);
  stageT(12288, 1);
  asm volatile("s_waitcnt vmcnt(3)" ::: "memory");
  __builtin_amdgcn_s_barrier();
  asm volatile("" ::: "memory");

  int pcur = 0, pnxt = 12288, pprv = 24576;  // slots of u, u+1, u+2 (mod 3)
  for (int u = 0; u < nt; ++u) {
    const bool pf = (u + 2 < nt);

    if (pf) stageT(pprv, u + 2);

    s16x8 a[4], b[4];
#pragma unroll
    for (int i = 0; i < 4; ++i)
      a[i] = lds_read8(smem, pcur + baseA + i * 512);
#pragma unroll
    for (int i = 0; i < 4; ++i)
      b[i] = lds_read8(smem, pcur + baseB + i * 512);

    __builtin_amdgcn_s_setprio(1);
#pragma unroll
    for (int mi = 0; mi < 4; ++mi)
#pragma unroll
      for (int ni = 0; ni < 4; ++ni)
        acc[mi][ni] = MFMA16(a[mi], b[ni], acc[mi][ni]);
    __builtin_amdgcn_s_setprio(0);

    asm volatile("s_waitcnt lgkmcnt(0)" ::: "memory");  // reads retired
    if (pf) {
      asm volatile("s_waitcnt vmcnt(3)" ::: "memory");  // tile u+1 resident
    } else {
      asm volatile("s_waitcnt vmcnt(0)" ::: "memory");  // tail drain
    }
    __builtin_amdgcn_s_barrier();  // publishes tile u+1 for next iteration
    asm volatile("" ::: "memory");

    const int tmp = pcur;
    pcur = pnxt;
    pnxt = pprv;
    pprv = tmp;
  }

  // Vectorized epilogue (wave-private LDS transpose; LDS free after loop).
  const int two = w * 1088;
  const int mb = bm * 128 + wm * 64;
  const int nb = bn * 256 + wn * 64;
#pragma unroll
  for (int m = 0; m < 4; ++m)
    epi_chunk<EPI>(smem, two, lane, acc[m], outp, bias, N, mb + m * 16, nb);
}

// ---------------------------------------------------------------------------
// Row LayerNorm over D=1024. Optional fp32 `add` (residual). Writes fp32
// and/or bf16. One block (256 thr) per row. Safe in-place (outf == in).
// ---------------------------------------------------------------------------
__global__ __launch_bounds__(256) void ln_k(
    const float* __restrict__ in, const float* __restrict__ add,
    const float* __restrict__ g, const float* __restrict__ b,
    float* __restrict__ outf, short* __restrict__ outb) {
  const int row = blockIdx.x;
  const size_t off = (size_t)row * 1024;
  const int t = threadIdx.x;
  float4 v = ((const float4*)(in + off))[t];
  if (add) {
    float4 w = ((const float4*)(add + off))[t];
    v.x += w.x; v.y += w.y; v.z += w.z; v.w += w.w;
  }
  float s = v.x + v.y + v.z + v.w;
  float ss = v.x * v.x + v.y * v.y + v.z * v.z + v.w * v.w;
#pragma unroll
  for (int o = 32; o > 0; o >>= 1) {
    s += __shfl_xor(s, o, 64);
    ss += __shfl_xor(ss, o, 64);
  }
  __shared__ float ps[4], pss[4];
  const int lane = t & 63, wave = t >> 6;
  if (lane == 0) { ps[wave] = s; pss[wave] = ss; }
  __syncthreads();
  s = ps[0] + ps[1] + ps[2] + ps[3];
  ss = pss[0] + pss[1] + pss[2] + pss[3];
  const float mean = s * (1.0f / 1024.0f);
  const float var = ss * (1.0f / 1024.0f) - mean * mean;
  const float rstd = rsqrtf(var + 1e-6f);
  const float4 gv = ((const float4*)g)[t];
  const float4 bv = ((const float4*)b)[t];
  float4 o4;
  o4.x = (v.x - mean) * rstd * gv.x + bv.x;
  o4.y = (v.y - mean) * rstd * gv.y + bv.y;
  o4.z = (v.z - mean) * rstd * gv.z + bv.z;
  o4.w = (v.w - mean) * rstd * gv.w + bv.w;
  if (outf) ((float4*)(outf + off))[t] = o4;
  if (outb) {
    s16x4 ob;
    ob[0] = f2bf(o4.x); ob[1] = f2bf(o4.y);
    ob[2] = f2bf(o4.z); ob[3] = f2bf(o4.w);
    *(s16x4*)(outb + off + t * 4) = ob;
  }
}

// ---------------------------------------------------------------------------
// Fused weight convert+transpose: all 7 weight matrices in ONE launch.
// ---------------------------------------------------------------------------
__device__ __forceinline__ void wconv_tile(const float* __restrict__ W,
                                           short* __restrict__ WT, int K,
                                           int N, int n0, int k0,
                                           float (*tile)[33], int c, int r) {
#pragma unroll
  for (int rr = r; rr < 32; rr += 8)
    tile[rr][c] = W[(size_t)(k0 + rr) * N + n0 + c];
  __syncthreads();
#pragma unroll
  for (int rr = r; rr < 32; rr += 8)
    WT[(size_t)(n0 + rr) * K + k0 + c] = f2bf(tile[c][rr]);
}

__global__ __launch_bounds__(256) void wconv_all(
    const float* __restrict__ wq, const float* __restrict__ wk,
    const float* __restrict__ wv, const float* __restrict__ wo,
    const float* __restrict__ w1, const float* __restrict__ w2,
    short* __restrict__ WQKVT, short* __restrict__ WOT,
    short* __restrict__ W1T, short* __restrict__ W2aT,
    short* __restrict__ W2bT) {
  __shared__ float tile[32][33];
  const int t = threadIdx.x;
  const int c = t & 31, r = t >> 5;
  const int i = blockIdx.x;
  if (i < 4096) {  // wq/wk/wv/wo: 1024x1024, 32x32 tiles each
    const int seg = i >> 10, j = i & 1023;
    const int n0 = (j & 31) * 32, k0 = (j >> 5) * 32;
    const float* src = (seg == 0) ? wq : (seg == 1) ? wk : (seg == 2) ? wv : wo;
    short* dst = (seg == 3) ? WOT : WQKVT + (size_t)seg * 1024 * 1024;
    wconv_tile(src, dst, 1024, 1024, n0, k0, tile, c, r);
  } else if (i < 8192) {  // w1: K=1024, N=4096
    const int j = i - 4096;
    const int n0 = (j & 127) * 32, k0 = (j >> 7) * 32;
    wconv_tile(w1, W1T, 1024, 4096, n0, k0, tile, c, r);
  } else if (i < 10240) {  // w2 rows 0-2047 -> W2aT
    const int j = i - 8192;
    const int n0 = (j & 31) * 32, k0 = (j >> 5) * 32;
    wconv_tile(w2, W2aT, 2048, 1024, n0, k0, tile, c, r);
  } else {  // w2 rows 2048-4095 -> W2bT
    const int j = i - 10240;
    const int n0 = (j & 31) * 32, k0 = (j >> 5) * 32;
    wconv_tile(w2 + (size_t)2048 * 1024, W2bT, 2048, 1024, n0, k0, tile, c, r);
  }
}

// ---------------------------------------------------------------------------
// Per-token head-mixing attention + faithful-reshape scramble.
// LDS rows padded: stride 65 (= 1 mod 32). Ps stride 17.
// ---------------------------------------------------------------------------
__global__ __launch_bounds__(256) void attn_k(const short* __restrict__ qkv,
                                              short* __restrict__ omix) {
  __shared__ float Qs[4][16][65];
  __shared__ float Ks[4][16][65];
  __shared__ float Vs[4][16][65];
  __shared__ float Ps[4][16][17];
  const int lane = threadIdx.x & 63;
  const int wave = threadIdx.x >> 6;
  const int tok = blockIdx.x * 4 + wave;
  const short* base = qkv + (size_t)tok * 3072;

#pragma unroll
  for (int half = 0; half < 2; half++) {
    const int e = half * 512 + lane * 8;
    const int h = e >> 6, d = e & 63;
    s16x8 rq = *(const s16x8*)(base + e);
    s16x8 rk = *(const s16x8*)(base + 1024 + e);
    s16x8 rv = *(const s16x8*)(base + 2048 + e);
#pragma unroll
    for (int j = 0; j < 8; j++) {
      Qs[wave][h][d + j] = bf2f(rq[j]);
      Ks[wave][h][d + j] = bf2f(rk[j]);
      Vs[wave][h][d + j] = bf2f(rv[j]);
    }
  }
  __syncthreads();

  const int h = lane & 15;
  const int g0 = (lane >> 4) * 4;
  float sc[4] = {0.f, 0.f, 0.f, 0.f};
  for (int d = 0; d < 64; d++) {
    const float qv = Qs[wave][h][d];
#pragma unroll
    for (int i = 0; i < 4; i++) sc[i] += qv * Ks[wave][g0 + i][d];
  }
#pragma unroll
  for (int i = 0; i < 4; i++) sc[i] *= 0.125f;
  float m = fmaxf(fmaxf(sc[0], sc[1]), fmaxf(sc[2], sc[3]));
  m = fmaxf(m, __shfl_xor(m, 16, 64));
  m = fmaxf(m, __shfl_xor(m, 32, 64));
  float e[4], sum = 0.f;
#pragma unroll
  for (int i = 0; i < 4; i++) { e[i] = __expf(sc[i] - m); sum += e[i]; }
  sum += __shfl_xor(sum, 16, 64);
  sum += __shfl_xor(sum, 32, 64);
  const float inv = __frcp_rn(sum);
#pragma unroll
  for (int i = 0; i < 4; i++) Ps[wave][h][g0 + i] = e[i] * inv;
  __syncthreads();

  const int d0 = (lane >> 4) * 16;
  float o[16];
#pragma unroll
  for (int dd = 0; dd < 16; dd++) o[dd] = 0.f;
  for (int gg = 0; gg < 16; gg++) {
    const float pv = Ps[wave][h][gg];
#pragma unroll
    for (int dd = 0; dd < 16; dd++) o[dd] += pv * Vs[wave][gg][d0 + dd];
  }

  const int b = tok >> 12, t = tok & 4095;
  const size_t dst =
      ((size_t)(b * 4096 + h * 256 + (t >> 4))) * 1024 + (t & 15) * 64 + d0;
  s16x8 w0, w1;
#pragma unroll
  for (int j = 0; j < 8; j++) { w0[j] = f2bf(o[j]); w1[j] = f2bf(o[8 + j]); }
  *(s16x8*)(omix + dst) = w0;
  *(s16x8*)(omix + dst + 8) = w1;
}

// ---------------------------------------------------------------------------
extern "C" void kernel_launch(void* const* d_in, const int* in_sizes, int n_in,
                              void* d_out, int out_size, void* d_ws,
                              size_t ws_size, hipStream_t stream) {
  const float* x    = (const float*)d_in[0];
  const float* wq   = (const float*)d_in[1];
  const float* wk   = (const float*)d_in[2];
  const float* wv   = (const float*)d_in[3];
  const float* wo   = (const float*)d_in[4];
  const float* ln1g = (const float*)d_in[5];
  const float* ln1b = (const float*)d_in[6];
  const float* w1   = (const float*)d_in[7];
  const float* b1   = (const float*)d_in[8];
  const float* w2   = (const float*)d_in[9];
  const float* b2   = (const float*)d_in[10];
  const float* ln2g = (const float*)d_in[11];
  const float* ln2b = (const float*)d_in[12];
  float* out = (float*)d_out;  // [16384,1024] f32; doubles as o2/q2 buffer

  char* ws = (char*)d_ws;
  const size_t MB = 1024ull * 1024ull;
  const size_t NEEDED = 152 * MB;
  if (ws_size < NEEDED) return;  // fail-numeric instead of page-fault

  short* QKV  = (short*)(ws + 0);        // phase1 [16384,3072] bf16
  short* Q2B  = (short*)(ws + 0);        // phase2 [16384,1024] bf16
  short* Hbuf = (short*)(ws + 32 * MB);  // phase2 [16384,2048] bf16
  short* X1 = (short*)(ws + 96 * MB);    // x1, then o_mixed bf16
  short* WQKVT = (short*)(ws + 128 * MB);
  short* WOT   = (short*)(ws + 134 * MB);
  short* W1T   = (short*)(ws + 136 * MB);
  short* W2aT  = (short*)(ws + 144 * MB);
  short* W2bT  = (short*)(ws + 148 * MB);

  const dim3 B256(256);
  const dim3 B512(512);
  const unsigned LDS256 = 131072;  // gemm256
  const unsigned LDS128 = 73728;   // gemm128 ring-3

  static bool attr_done = false;
  if (!attr_done) {
    attr_done = true;
    void (*k0)(const short*, const short*, void*, const float*, int, int) =
        gemm256<0>;
    void (*k2)(const short*, const short*, void*, const float*, int, int) =
        gemm256<2>;
    (void)hipFuncSetAttribute((const void*)k0,
        hipFuncAttributeMaxDynamicSharedMemorySize, (int)LDS256);
    (void)hipFuncSetAttribute((const void*)k2,
        hipFuncAttributeMaxDynamicSharedMemorySize, (int)LDS256);
    void (*h1)(const short*, const short*, void*, const float*, int, int) =
        gemm128<1>;
    void (*h4)(const short*, const short*, void*, const float*, int, int) =
        gemm128<4>;
    (void)hipFuncSetAttribute((const void*)h1,
        hipFuncAttributeMaxDynamicSharedMemorySize, (int)LDS128);
    (void)hipFuncSetAttribute((const void*)h4,
        hipFuncAttributeMaxDynamicSharedMemorySize, (int)LDS128);
  }

  // All weight conversions in one launch.
  wconv_all<<<dim3(12288), B256, 0, stream>>>(wq, wk, wv, wo, w1, w2, WQKVT,
                                              WOT, W1T, W2aT, W2bT);

  // x1 = LN1(x) -> bf16
  ln_k<<<16384, B256, 0, stream>>>(x, nullptr, ln1g, ln1b, nullptr, X1);

  // QKV = x1 @ [wq|wk|wv]   (gemm256 single-phase, grid 768)
  gemm256<0><<<dim3(768), B512, LDS256, stream>>>(X1, WQKVT, QKV, nullptr,
                                                  3072, 1024);

  // attention + scramble -> o_mixed (reuses X1 region)
  attn_k<<<4096, B256, 0, stream>>>(QKV, X1);

  // o2 = o_mixed @ wo -> f32 into d_out   (gemm128 ring-3: grid 512)
  gemm128<1><<<dim3(512), B512, LDS128, stream>>>(X1, WOT, out, nullptr,
                                                  1024, 1024);

  // q2 = LN1(o2 + x): f32 in-place in d_out, bf16 copy in Q2B
  ln_k<<<16384, B256, 0, stream>>>(out, x, ln1g, ln1b, out, Q2B);

  // FFN half A  (W1: gemm256 grid 512 = 2 rounds/CU; W2: gemm128 grid 512)
  gemm256<2><<<dim3(512), B512, LDS256, stream>>>(Q2B, W1T, Hbuf, b1,
                                                  2048, 1024);
  gemm128<4><<<dim3(512), B512, LDS128, stream>>>(Hbuf, W2aT, out, nullptr,
                                                  1024, 2048);

  // FFN half B
  gemm256<2><<<dim3(512), B512, LDS256, stream>>>(Q2B, W1T + 2048 * 1024,
                                                  Hbuf, b1 + 2048, 2048,
                                                  1024);
  gemm128<4><<<dim3(512), B512, LDS128, stream>>>(Hbuf, W2bT, out, b2,
                                                  1024, 2048);

  // out = LN2(y) in-place
  ln_k<<<16384, B256, 0, stream>>>(out, nullptr, ln2g, ln2b, out, nullptr);
}

// Round 16
// 760.966 us; speedup vs baseline: 1.0486x; 1.0213x over previous
//
#include <hip/hip_runtime.h>

// Encoder block: LN1 -> QKV -> per-token head-mix attention -> scramble ->
// WO -> +x,LN1 -> W1+GELU (2 halves) -> W2 accum (+b2,+q2) -> LN2 in-place.
//
// r16 = r12/r15 (measured-best GEMM configuration, untouched) with ONE
// non-GEMM change: the two head launches (wconv_all + LN1-of-x) fused into
// a single kernel `wconv_ln` (grid 28672). Both are independent
// memory-bound streams (~150 MB weights + ~96 MB x/X1); fusing overlaps
// their DRAM traffic and removes a launch/drain boundary. No GEMM template
// touched (r13/r14 showed gemm-template edits re-roll sibling codegen
// by +-30-60 us; run-to-run noise is +-10 us — r15 byte-identical to r12
// measured 777.2 vs 767.4).
//
//  gemm256 (single-phase, r8): 256x256 / BK=64 / 8 waves / 128 KiB LDS.
//    QKV (grid 768) + W1 halves (grid 512; >=2 rounds/CU regime).
//  gemm128 (ring-3, r9): 128x256 / BK=32 / 8 waves / 72 KiB LDS (3 slots),
//    ONE barrier/K-tile, (512,4) VGPR budget 128. WO + W2 halves (grid 512,
//    2 blocks/CU; N=1024 on gemm256 would be the measured-bad 1-round).
//  Epilogues: vectorized (per-wave LDS transpose, 64 cols x 17-f32 stride;
//  wide s16x8/float4 stores; EPI=4 float4 prev-reads).
//  XCD mapping (both): bm-banded / bn-fastest (A band L2-resident per XCD).
//
// attn_k: LDS rows padded to 65 floats (16-way bank conflict fix, r7).
// Workspace footprint: 152 MB (d_out doubles as the f32 residual buffer).

typedef __attribute__((ext_vector_type(8))) short s16x8;
typedef __attribute__((ext_vector_type(4))) short s16x4;
typedef __attribute__((ext_vector_type(4))) float f32x4;

__device__ __forceinline__ short f2bf(float x) {
  unsigned u = __builtin_bit_cast(unsigned, x);
  u = (u + 0x7FFFu + ((u >> 16) & 1u)) >> 16;
  return (short)u;
}
__device__ __forceinline__ float bf2f(short s) {
  unsigned u = ((unsigned)(unsigned short)s) << 16;
  return __builtin_bit_cast(float, u);
}

__device__ __forceinline__ void ld_g2l16(const short* g, const short* l) {
  __builtin_amdgcn_global_load_lds(
      (const __attribute__((address_space(1))) void*)g,
      (__attribute__((address_space(3))) void*)l, 16, 0, 0);
}

// Guaranteed-DS accesses: explicit addrspace(3) so codegen emits ds_* ops.
__device__ __forceinline__ s16x8 lds_read8(const short* smem, int off) {
  const __attribute__((address_space(3))) short* p =
      (const __attribute__((address_space(3))) short*)smem;
  return *(const __attribute__((address_space(3))) s16x8*)(p + off);
}
__device__ __forceinline__ void lds_wr_f32(const short* smem, int foff,
                                           float v) {
  __attribute__((address_space(3))) float* p =
      (__attribute__((address_space(3))) float*)smem;
  p[foff] = v;
}
__device__ __forceinline__ float lds_rd_f32(const short* smem, int foff) {
  const __attribute__((address_space(3))) float* p =
      (const __attribute__((address_space(3))) float*)smem;
  return p[foff];
}

// Fast GELU (tanh form via v_exp_f32; |err| ~1e-3 << bf16 noise).
__device__ __forceinline__ float fast_gelu(float v) {
  float y = 0.7978845608f * (v + 0.044715f * v * v * v);
  float ay = fabsf(y);
  float t = __expf(-2.0f * ay);
  float th = (1.0f - t) * __frcp_rn(1.0f + t);
  th = (y >= 0.f) ? th : -th;
  return 0.5f * v * (1.0f + th);
}

#define MFMA16(va, vb, vc) \
  __builtin_amdgcn_mfma_f32_16x16x32_bf16(va, vb, vc, 0, 0, 0)

// Shared vectorized epilogue body. Writes one 16-row chunk of a wave's
// 64-col tile. t-region: wave-private, f32 offset `two`, stride 17.
// EPI: 0 bf16; 1 f32; 2 +bias,GELU,bf16; 4 f32 accum (+bias).
template <int EPI>
__device__ __forceinline__ void epi_chunk(
    const short* smem, int two, int lane, const f32x4* accm /*[4]*/,
    void* __restrict__ outp, const float* __restrict__ bias, int N, int rowb,
    int nb) {
  const int cc16 = lane & 15, hq = lane >> 4;
#pragma unroll
  for (int n = 0; n < 4; ++n)
#pragma unroll
    for (int r = 0; r < 4; ++r)
      lds_wr_f32(smem, two + (n * 16 + cc16) * 17 + hq * 4 + r, accm[n][r]);
  asm volatile("s_waitcnt lgkmcnt(0)" ::: "memory");
  if constexpr (EPI == 0 || EPI == 2) {
    const int grp = lane & 7;
#pragma unroll
    for (int p = 0; p < 2; ++p) {
      const int row = p * 8 + (lane >> 3);
      const int colb = grp * 8;
      s16x8 ov;
#pragma unroll
      for (int i = 0; i < 8; ++i) {
        float v = lds_rd_f32(smem, two + (colb + i) * 17 + row);
        if constexpr (EPI == 2) v = fast_gelu(v + bias[nb + colb + i]);
        ov[i] = f2bf(v);
      }
      *(s16x8*)((short*)outp + (size_t)(rowb + row) * N + nb + colb) = ov;
    }
  } else {
    const int seg = lane & 3;
    const int row = lane >> 2;
#pragma unroll
    for (int k = 0; k < 4; ++k) {
      const int colb = seg * 4 + k * 16;
      float4 v4;
      v4.x = lds_rd_f32(smem, two + (colb + 0) * 17 + row);
      v4.y = lds_rd_f32(smem, two + (colb + 1) * 17 + row);
      v4.z = lds_rd_f32(smem, two + (colb + 2) * 17 + row);
      v4.w = lds_rd_f32(smem, two + (colb + 3) * 17 + row);
      float* gp = (float*)outp + (size_t)(rowb + row) * N + nb + colb;
      if constexpr (EPI == 4) {
        float4 pv = *(const float4*)gp;
        v4.x += pv.x; v4.y += pv.y; v4.z += pv.z; v4.w += pv.w;
        if (bias) {
          v4.x += bias[nb + colb + 0];
          v4.y += bias[nb + colb + 1];
          v4.z += bias[nb + colb + 2];
          v4.w += bias[nb + colb + 3];
        }
      }
      *(float4*)gp = v4;
    }
  }
  asm volatile("s_waitcnt lgkmcnt(0)" ::: "memory");
}

// ---------------------------------------------------------------------------
// gemm256: C[M,N] = A[M,K] @ BT[N,K]^T. M=16384. N,K multiples of 256.
// grid = 64*(N/256), 512 thr, dyn LDS 131072 B.  (r8 single-phase loop)
// ---------------------------------------------------------------------------
template <int EPI>
__global__ __launch_bounds__(512, 2) void gemm256(
    const short* __restrict__ A, const short* __restrict__ BT,
    void* __restrict__ outp, const float* __restrict__ bias, int N, int K) {
  extern __shared__ __align__(16) short smem[];

  const int t = threadIdx.x;
  const int lane = t & 63, w = t >> 6;
  const int wm = w >> 2, wn = w & 3;  // wave tile: rows wm*128, cols wn*64

  const int nbn = N >> 8;
  const int oi = (int)blockIdx.x;
  const int seq = oi >> 3;
  const int bq = seq / nbn;
  const int bm = (oi & 7) * 8 + bq;
  const int bn = seq - bq * nbn;

  const int l8 = lane >> 3;
  const int lcw = ((lane & 7) ^ l8) * 8;  // swizzled chunk offset (shorts)
  const short* gA = A + (size_t)(bm * 256 + w * 8 + l8) * K + lcw;
  const short* gB = BT + (size_t)(bn * 256 + w * 8 + l8) * K + lcw;
  const int lb = w * 512;

  auto stage = [&](const short* g, int bufo, int h, int kt) {
    const int go = h * 128 * K + kt * 64;
    ld_g2l16(g + go, smem + bufo + h * 8192 + lb);                  // q = 0
    ld_g2l16(g + go + 64 * K, smem + bufo + h * 8192 + 4096 + lb);  // q = 1
  };

  const int fr = lane & 15, fc = lane >> 4;
  const int baseA = (wm * 128 + fr) * 64;
  const int baseB = (wn * 64 + fr) * 64;
  const int sl0 = (fc ^ (fr & 7)) * 8;
  const int sl1 = ((4 + fc) ^ (fr & 7)) * 8;

  f32x4 acc[8][4];
#pragma unroll
  for (int m = 0; m < 8; ++m)
#pragma unroll
    for (int n = 0; n < 4; ++n) acc[m][n] = (f32x4){0.f, 0.f, 0.f, 0.f};

  const int nt = K >> 6;

  stage(gA, 0, 0, 0);
  stage(gA, 0, 1, 0);
  stage(gB, 32768, 0, 0);
  stage(gB, 32768, 1, 0);
  if (nt > 1) {
    stage(gA, 16384, 0, 1);
    stage(gA, 16384, 1, 1);
    stage(gB, 49152, 0, 1);
    stage(gB, 49152, 1, 1);
    asm volatile("s_waitcnt vmcnt(8)" ::: "memory");
  } else {
    asm volatile("s_waitcnt vmcnt(0)" ::: "memory");
  }
  __builtin_amdgcn_s_barrier();
  asm volatile("" ::: "memory");

  for (int u = 0; u < nt; ++u) {
    const bool pf = (u + 2 < nt);
    const int pa = (u & 1) << 14;
    const int pb = 32768 + pa;

    s16x8 a0[4][2], a1[4][2], b0[2][2], b1[2][2];
#pragma unroll
    for (int mi = 0; mi < 4; ++mi) {
      a0[mi][0] = lds_read8(smem, pa + baseA + mi * 1024 + sl0);
      a0[mi][1] = lds_read8(smem, pa + baseA + mi * 1024 + sl1);
    }
#pragma unroll
    for (int ni = 0; ni < 2; ++ni) {
      b0[ni][0] = lds_read8(smem, pb + baseB + ni * 1024 + sl0);
      b0[ni][1] = lds_read8(smem, pb + baseB + ni * 1024 + sl1);
    }
#pragma unroll
    for (int ni = 0; ni < 2; ++ni) {
      b1[ni][0] = lds_read8(smem, pb + baseB + 2048 + ni * 1024 + sl0);
      b1[ni][1] = lds_read8(smem, pb + baseB + 2048 + ni * 1024 + sl1);
    }
#pragma unroll
    for (int mi = 0; mi < 4; ++mi) {
      a1[mi][0] = lds_read8(smem, pa + baseA + 4096 + mi * 1024 + sl0);
      a1[mi][1] = lds_read8(smem, pa + baseA + 4096 + mi * 1024 + sl1);
    }

    __builtin_amdgcn_s_setprio(1);
#pragma unroll
    for (int mi = 0; mi < 4; ++mi)
#pragma unroll
      for (int ni = 0; ni < 2; ++ni) {
        acc[mi][ni] = MFMA16(a0[mi][0], b0[ni][0], acc[mi][ni]);
        acc[mi][ni] = MFMA16(a0[mi][1], b0[ni][1], acc[mi][ni]);
      }
#pragma unroll
    for (int mi = 0; mi < 4; ++mi)
#pragma unroll
      for (int ni = 0; ni < 2; ++ni) {
        acc[mi][2 + ni] = MFMA16(a0[mi][0], b1[ni][0], acc[mi][2 + ni]);
        acc[mi][2 + ni] = MFMA16(a0[mi][1], b1[ni][1], acc[mi][2 + ni]);
      }
#pragma unroll
    for (int mi = 0; mi < 4; ++mi)
#pragma unroll
      for (int ni = 0; ni < 2; ++ni) {
        acc[4 + mi][2 + ni] = MFMA16(a1[mi][0], b1[ni][0], acc[4 + mi][2 + ni]);
        acc[4 + mi][2 + ni] = MFMA16(a1[mi][1], b1[ni][1], acc[4 + mi][2 + ni]);
      }
    __builtin_amdgcn_s_setprio(0);

    asm volatile("s_waitcnt lgkmcnt(0)" ::: "memory");  // free (consumed)
    __builtin_amdgcn_s_barrier();
    asm volatile("" ::: "memory");

    if (pf) {
      stage(gB, pb, 0, u + 2);
      stage(gB, pb, 1, u + 2);
      stage(gA, pa, 0, u + 2);
      stage(gA, pa, 1, u + 2);
    }

    __builtin_amdgcn_s_setprio(1);
#pragma unroll
    for (int mi = 0; mi < 4; ++mi)
#pragma unroll
      for (int ni = 0; ni < 2; ++ni) {
        acc[4 + mi][ni] = MFMA16(a1[mi][0], b0[ni][0], acc[4 + mi][ni]);
        acc[4 + mi][ni] = MFMA16(a1[mi][1], b0[ni][1], acc[4 + mi][ni]);
      }
    __builtin_amdgcn_s_setprio(0);

    if (pf) {
      asm volatile("s_waitcnt vmcnt(8)" ::: "memory");
    } else {
      asm volatile("s_waitcnt vmcnt(0)" ::: "memory");
    }
    __builtin_amdgcn_s_barrier();
    asm volatile("" ::: "memory");
  }

  // Vectorized epilogue (wave-private LDS transpose; LDS free after loop).
  const int two = w * 1088;  // f32 offset of wave region (4352 B each)
  const int mb = bm * 256 + wm * 128;
  const int nb = bn * 256 + wn * 64;
#pragma unroll
  for (int m = 0; m < 8; ++m)
    epi_chunk<EPI>(smem, two, lane, acc[m], outp, bias, N, mb + m * 16, nb);
}

// ---------------------------------------------------------------------------
// gemm128 RING-3: tile 128x256, BK=32, 8 waves (2Mx4N, wave 64x64).
// LDS = 3 parity slots x 24 KB = 73728 B. ONE barrier + one counted vmcnt
// per K-tile. __launch_bounds__(512,4): 2 blocks/CU. grid = 128*(N/256).
// ---------------------------------------------------------------------------
template <int EPI>
__global__ __launch_bounds__(512, 4) void gemm128(
    const short* __restrict__ A, const short* __restrict__ BT,
    void* __restrict__ outp, const float* __restrict__ bias, int N, int K) {
  extern __shared__ __align__(16) short smem[];

  const int t = threadIdx.x;
  const int lane = t & 63, w = t >> 6;
  const int wm = w >> 2, wn = w & 3;  // wave tile: rows wm*64, cols wn*64

  // bm-banded / bn-fastest XCD mapping; nbm = 128 (M = 16384).
  const int nbn = N >> 8;
  const int oi = (int)blockIdx.x;
  const int seq = oi >> 3;
  const int bq = seq / nbn;
  const int bm = (oi & 7) * 16 + bq;
  const int bn = seq - bq * nbn;

  // Staging: lane -> (row = lane>>2, LDS slot = lane&3); global chunk
  // pre-rotated: c = ((lane&3) - ((lane>>3)&3)) & 3.
  const int lr = lane >> 2;
  const int lc = ((lane & 3) - ((lane >> 3) & 3)) & 3;
  const short* gA = A + (size_t)(bm * 128 + lr) * K + lc * 8;
  const short* gB = BT + (size_t)(bn * 256 + lr) * K + lc * 8;

  auto stageT = [&](int par, int kt) {
    ld_g2l16(gA + (size_t)(w * 16) * K + kt * 32, smem + par + w * 512);
    ld_g2l16(gB + (size_t)(2 * w * 16) * K + kt * 32,
             smem + par + 4096 + 2 * w * 512);
    ld_g2l16(gB + (size_t)((2 * w + 1) * 16) * K + kt * 32,
             smem + par + 4096 + (2 * w + 1) * 512);
  };

  const int fr = lane & 15, fc = lane >> 4;
  const int sl = ((fc + (fr >> 1)) & 3) * 8;
  const int baseA = (wm * 64 + fr) * 32 + sl;
  const int baseB = 4096 + (wn * 64 + fr) * 32 + sl;

  f32x4 acc[4][4];
#pragma unroll
  for (int m = 0; m < 4; ++m)
#pragma unroll
    for (int n = 0; n < 4; ++n) acc[m][n] = (f32x4){0.f, 0.f, 0.f, 0.f};

  const int nt = K >> 5;

  stageT(0, 0);
  stageT(12288, 1);
  asm volatile("s_waitcnt vmcnt(3)" ::: "memory");
  __builtin_amdgcn_s_barrier();
  asm volatile("" ::: "memory");

  int pcur = 0, pnxt = 12288, pprv = 24576;  // slots of u, u+1, u+2 (mod 3)
  for (int u = 0; u < nt; ++u) {
    const bool pf = (u + 2 < nt);

    if (pf) stageT(pprv, u + 2);

    s16x8 a[4], b[4];
#pragma unroll
    for (int i = 0; i < 4; ++i)
      a[i] = lds_read8(smem, pcur + baseA + i * 512);
#pragma unroll
    for (int i = 0; i < 4; ++i)
      b[i] = lds_read8(smem, pcur + baseB + i * 512);

    __builtin_amdgcn_s_setprio(1);
#pragma unroll
    for (int mi = 0; mi < 4; ++mi)
#pragma unroll
      for (int ni = 0; ni < 4; ++ni)
        acc[mi][ni] = MFMA16(a[mi], b[ni], acc[mi][ni]);
    __builtin_amdgcn_s_setprio(0);

    asm volatile("s_waitcnt lgkmcnt(0)" ::: "memory");  // reads retired
    if (pf) {
      asm volatile("s_waitcnt vmcnt(3)" ::: "memory");  // tile u+1 resident
    } else {
      asm volatile("s_waitcnt vmcnt(0)" ::: "memory");  // tail drain
    }
    __builtin_amdgcn_s_barrier();  // publishes tile u+1 for next iteration
    asm volatile("" ::: "memory");

    const int tmp = pcur;
    pcur = pnxt;
    pnxt = pprv;
    pprv = tmp;
  }

  // Vectorized epilogue (wave-private LDS transpose; LDS free after loop).
  const int two = w * 1088;
  const int mb = bm * 128 + wm * 64;
  const int nb = bn * 256 + wn * 64;
#pragma unroll
  for (int m = 0; m < 4; ++m)
    epi_chunk<EPI>(smem, two, lane, acc[m], outp, bias, N, mb + m * 16, nb);
}

// ---------------------------------------------------------------------------
// Row LayerNorm over D=1024. Optional fp32 `add` (residual). Writes fp32
// and/or bf16. One block (256 thr) per row. Safe in-place (outf == in).
// ---------------------------------------------------------------------------
__global__ __launch_bounds__(256) void ln_k(
    const float* __restrict__ in, const float* __restrict__ add,
    const float* __restrict__ g, const float* __restrict__ b,
    float* __restrict__ outf, short* __restrict__ outb) {
  const int row = blockIdx.x;
  const size_t off = (size_t)row * 1024;
  const int t = threadIdx.x;
  float4 v = ((const float4*)(in + off))[t];
  if (add) {
    float4 w = ((const float4*)(add + off))[t];
    v.x += w.x; v.y += w.y; v.z += w.z; v.w += w.w;
  }
  float s = v.x + v.y + v.z + v.w;
  float ss = v.x * v.x + v.y * v.y + v.z * v.z + v.w * v.w;
#pragma unroll
  for (int o = 32; o > 0; o >>= 1) {
    s += __shfl_xor(s, o, 64);
    ss += __shfl_xor(ss, o, 64);
  }
  __shared__ float ps[4], pss[4];
  const int lane = t & 63, wave = t >> 6;
  if (lane == 0) { ps[wave] = s; pss[wave] = ss; }
  __syncthreads();
  s = ps[0] + ps[1] + ps[2] + ps[3];
  ss = pss[0] + pss[1] + pss[2] + pss[3];
  const float mean = s * (1.0f / 1024.0f);
  const float var = ss * (1.0f / 1024.0f) - mean * mean;
  const float rstd = rsqrtf(var + 1e-6f);
  const float4 gv = ((const float4*)g)[t];
  const float4 bv = ((const float4*)b)[t];
  float4 o4;
  o4.x = (v.x - mean) * rstd * gv.x + bv.x;
  o4.y = (v.y - mean) * rstd * gv.y + bv.y;
  o4.z = (v.z - mean) * rstd * gv.z + bv.z;
  o4.w = (v.w - mean) * rstd * gv.w + bv.w;
  if (outf) ((float4*)(outf + off))[t] = o4;
  if (outb) {
    s16x4 ob;
    ob[0] = f2bf(o4.x); ob[1] = f2bf(o4.y);
    ob[2] = f2bf(o4.z); ob[3] = f2bf(o4.w);
    *(s16x4*)(outb + off + t * 4) = ob;
  }
}

// ---------------------------------------------------------------------------
// Fused head: weight convert+transpose (blocks 0..12287) AND LN1(x)->bf16
// (blocks 12288..28671, one row each). Independent memory-bound streams;
// fusing overlaps their DRAM traffic and removes one launch boundary.
// ---------------------------------------------------------------------------
__device__ __forceinline__ void wconv_tile(const float* __restrict__ W,
                                           short* __restrict__ WT, int K,
                                           int N, int n0, int k0,
                                           float (*tile)[33], int c, int r) {
#pragma unroll
  for (int rr = r; rr < 32; rr += 8)
    tile[rr][c] = W[(size_t)(k0 + rr) * N + n0 + c];
  __syncthreads();
#pragma unroll
  for (int rr = r; rr < 32; rr += 8)
    WT[(size_t)(n0 + rr) * K + k0 + c] = f2bf(tile[c][rr]);
}

__global__ __launch_bounds__(256) void wconv_ln(
    const float* __restrict__ wq, const float* __restrict__ wk,
    const float* __restrict__ wv, const float* __restrict__ wo,
    const float* __restrict__ w1, const float* __restrict__ w2,
    const float* __restrict__ x, const float* __restrict__ ln1g,
    const float* __restrict__ ln1b, short* __restrict__ WQKVT,
    short* __restrict__ WOT, short* __restrict__ W1T,
    short* __restrict__ W2aT, short* __restrict__ W2bT,
    short* __restrict__ X1) {
  __shared__ float tile[32][33];
  __shared__ float ps[4], pss[4];
  const int t = threadIdx.x;
  const int i = blockIdx.x;
  if (i < 12288) {  // ---- weight conversion path
    const int c = t & 31, r = t >> 5;
    if (i < 4096) {  // wq/wk/wv/wo: 1024x1024, 32x32 tiles each
      const int seg = i >> 10, j = i & 1023;
      const int n0 = (j & 31) * 32, k0 = (j >> 5) * 32;
      const float* src =
          (seg == 0) ? wq : (seg == 1) ? wk : (seg == 2) ? wv : wo;
      short* dst = (seg == 3) ? WOT : WQKVT + (size_t)seg * 1024 * 1024;
      wconv_tile(src, dst, 1024, 1024, n0, k0, tile, c, r);
    } else if (i < 8192) {  // w1: K=1024, N=4096
      const int j = i - 4096;
      const int n0 = (j & 127) * 32, k0 = (j >> 7) * 32;
      wconv_tile(w1, W1T, 1024, 4096, n0, k0, tile, c, r);
    } else if (i < 10240) {  // w2 rows 0-2047 -> W2aT
      const int j = i - 8192;
      const int n0 = (j & 31) * 32, k0 = (j >> 5) * 32;
      wconv_tile(w2, W2aT, 2048, 1024, n0, k0, tile, c, r);
    } else {  // w2 rows 2048-4095 -> W2bT
      const int j = i - 10240;
      const int n0 = (j & 31) * 32, k0 = (j >> 5) * 32;
      wconv_tile(w2 + (size_t)2048 * 1024, W2bT, 2048, 1024, n0, k0, tile, c,
                 r);
    }
  } else {  // ---- LN1(x) -> X1 bf16 path (one row per block)
    const int row = i - 12288;
    const size_t off = (size_t)row * 1024;
    float4 v = ((const float4*)(x + off))[t];
    float s = v.x + v.y + v.z + v.w;
    float ss = v.x * v.x + v.y * v.y + v.z * v.z + v.w * v.w;
#pragma unroll
    for (int o = 32; o > 0; o >>= 1) {
      s += __shfl_xor(s, o, 64);
      ss += __shfl_xor(ss, o, 64);
    }
    const int lane = t & 63, wave = t >> 6;
    if (lane == 0) { ps[wave] = s; pss[wave] = ss; }
    __syncthreads();
    s = ps[0] + ps[1] + ps[2] + ps[3];
    ss = pss[0] + pss[1] + pss[2] + pss[3];
    const float mean = s * (1.0f / 1024.0f);
    const float var = ss * (1.0f / 1024.0f) - mean * mean;
    const float rstd = rsqrtf(var + 1e-6f);
    const float4 gv = ((const float4*)ln1g)[t];
    const float4 bv = ((const float4*)ln1b)[t];
    s16x4 ob;
    ob[0] = f2bf((v.x - mean) * rstd * gv.x + bv.x);
    ob[1] = f2bf((v.y - mean) * rstd * gv.y + bv.y);
    ob[2] = f2bf((v.z - mean) * rstd * gv.z + bv.z);
    ob[3] = f2bf((v.w - mean) * rstd * gv.w + bv.w);
    *(s16x4*)(X1 + off + t * 4) = ob;
  }
}

// ---------------------------------------------------------------------------
// Per-token head-mixing attention + faithful-reshape scramble.
// LDS rows padded: stride 65 (= 1 mod 32). Ps stride 17.
// ---------------------------------------------------------------------------
__global__ __launch_bounds__(256) void attn_k(const short* __restrict__ qkv,
                                              short* __restrict__ omix) {
  __shared__ float Qs[4][16][65];
  __shared__ float Ks[4][16][65];
  __shared__ float Vs[4][16][65];
  __shared__ float Ps[4][16][17];
  const int lane = threadIdx.x & 63;
  const int wave = threadIdx.x >> 6;
  const int tok = blockIdx.x * 4 + wave;
  const short* base = qkv + (size_t)tok * 3072;

#pragma unroll
  for (int half = 0; half < 2; half++) {
    const int e = half * 512 + lane * 8;
    const int h = e >> 6, d = e & 63;
    s16x8 rq = *(const s16x8*)(base + e);
    s16x8 rk = *(const s16x8*)(base + 1024 + e);
    s16x8 rv = *(const s16x8*)(base + 2048 + e);
#pragma unroll
    for (int j = 0; j < 8; j++) {
      Qs[wave][h][d + j] = bf2f(rq[j]);
      Ks[wave][h][d + j] = bf2f(rk[j]);
      Vs[wave][h][d + j] = bf2f(rv[j]);
    }
  }
  __syncthreads();

  const int h = lane & 15;
  const int g0 = (lane >> 4) * 4;
  float sc[4] = {0.f, 0.f, 0.f, 0.f};
  for (int d = 0; d < 64; d++) {
    const float qv = Qs[wave][h][d];
#pragma unroll
    for (int i = 0; i < 4; i++) sc[i] += qv * Ks[wave][g0 + i][d];
  }
#pragma unroll
  for (int i = 0; i < 4; i++) sc[i] *= 0.125f;
  float m = fmaxf(fmaxf(sc[0], sc[1]), fmaxf(sc[2], sc[3]));
  m = fmaxf(m, __shfl_xor(m, 16, 64));
  m = fmaxf(m, __shfl_xor(m, 32, 64));
  float e[4], sum = 0.f;
#pragma unroll
  for (int i = 0; i < 4; i++) { e[i] = __expf(sc[i] - m); sum += e[i]; }
  sum += __shfl_xor(sum, 16, 64);
  sum += __shfl_xor(sum, 32, 64);
  const float inv = __frcp_rn(sum);
#pragma unroll
  for (int i = 0; i < 4; i++) Ps[wave][h][g0 + i] = e[i] * inv;
  __syncthreads();

  const int d0 = (lane >> 4) * 16;
  float o[16];
#pragma unroll
  for (int dd = 0; dd < 16; dd++) o[dd] = 0.f;
  for (int gg = 0; gg < 16; gg++) {
    const float pv = Ps[wave][h][gg];
#pragma unroll
    for (int dd = 0; dd < 16; dd++) o[dd] += pv * Vs[wave][gg][d0 + dd];
  }

  const int b = tok >> 12, t = tok & 4095;
  const size_t dst =
      ((size_t)(b * 4096 + h * 256 + (t >> 4))) * 1024 + (t & 15) * 64 + d0;
  s16x8 w0, w1;
#pragma unroll
  for (int j = 0; j < 8; j++) { w0[j] = f2bf(o[j]); w1[j] = f2bf(o[8 + j]); }
  *(s16x8*)(omix + dst) = w0;
  *(s16x8*)(omix + dst + 8) = w1;
}

// ---------------------------------------------------------------------------
extern "C" void kernel_launch(void* const* d_in, const int* in_sizes, int n_in,
                              void* d_out, int out_size, void* d_ws,
                              size_t ws_size, hipStream_t stream) {
  const float* x    = (const float*)d_in[0];
  const float* wq   = (const float*)d_in[1];
  const float* wk   = (const float*)d_in[2];
  const float* wv   = (const float*)d_in[3];
  const float* wo   = (const float*)d_in[4];
  const float* ln1g = (const float*)d_in[5];
  const float* ln1b = (const float*)d_in[6];
  const float* w1   = (const float*)d_in[7];
  const float* b1   = (const float*)d_in[8];
  const float* w2   = (const float*)d_in[9];
  const float* b2   = (const float*)d_in[10];
  const float* ln2g = (const float*)d_in[11];
  const float* ln2b = (const float*)d_in[12];
  float* out = (float*)d_out;  // [16384,1024] f32; doubles as o2/q2 buffer

  char* ws = (char*)d_ws;
  const size_t MB = 1024ull * 1024ull;
  const size_t NEEDED = 152 * MB;
  if (ws_size < NEEDED) return;  // fail-numeric instead of page-fault

  short* QKV  = (short*)(ws + 0);        // phase1 [16384,3072] bf16
  short* Q2B  = (short*)(ws + 0);        // phase2 [16384,1024] bf16
  short* Hbuf = (short*)(ws + 32 * MB);  // phase2 [16384,2048] bf16
  short* X1 = (short*)(ws + 96 * MB);    // x1, then o_mixed bf16
  short* WQKVT = (short*)(ws + 128 * MB);
  short* WOT   = (short*)(ws + 134 * MB);
  short* W1T   = (short*)(ws + 136 * MB);
  short* W2aT  = (short*)(ws + 144 * MB);
  short* W2bT  = (short*)(ws + 148 * MB);

  const dim3 B256(256);
  const dim3 B512(512);
  const unsigned LDS256 = 131072;  // gemm256
  const unsigned LDS128 = 73728;   // gemm128 ring-3

  static bool attr_done = false;
  if (!attr_done) {
    attr_done = true;
    void (*k0)(const short*, const short*, void*, const float*, int, int) =
        gemm256<0>;
    void (*k2)(const short*, const short*, void*, const float*, int, int) =
        gemm256<2>;
    (void)hipFuncSetAttribute((const void*)k0,
        hipFuncAttributeMaxDynamicSharedMemorySize, (int)LDS256);
    (void)hipFuncSetAttribute((const void*)k2,
        hipFuncAttributeMaxDynamicSharedMemorySize, (int)LDS256);
    void (*h1)(const short*, const short*, void*, const float*, int, int) =
        gemm128<1>;
    void (*h4)(const short*, const short*, void*, const float*, int, int) =
        gemm128<4>;
    (void)hipFuncSetAttribute((const void*)h1,
        hipFuncAttributeMaxDynamicSharedMemorySize, (int)LDS128);
    (void)hipFuncSetAttribute((const void*)h4,
        hipFuncAttributeMaxDynamicSharedMemorySize, (int)LDS128);
  }

  // Fused head: all weight conversions + LN1(x)->X1 in ONE launch.
  wconv_ln<<<dim3(28672), B256, 0, stream>>>(wq, wk, wv, wo, w1, w2, x, ln1g,
                                             ln1b, WQKVT, WOT, W1T, W2aT,
                                             W2bT, X1);

  // QKV = x1 @ [wq|wk|wv]   (gemm256 single-phase, grid 768)
  gemm256<0><<<dim3(768), B512, LDS256, stream>>>(X1, WQKVT, QKV, nullptr,
                                                  3072, 1024);

  // attention + scramble -> o_mixed (reuses X1 region)
  attn_k<<<4096, B256, 0, stream>>>(QKV, X1);

  // o2 = o_mixed @ wo -> f32 into d_out   (gemm128 ring-3: grid 512)
  gemm128<1><<<dim3(512), B512, LDS128, stream>>>(X1, WOT, out, nullptr,
                                                  1024, 1024);

  // q2 = LN1(o2 + x): f32 in-place in d_out, bf16 copy in Q2B
  ln_k<<<16384, B256, 0, stream>>>(out, x, ln1g, ln1b, out, Q2B);

  // FFN half A  (W1: gemm256 grid 512 = 2 rounds/CU; W2: gemm128 grid 512)
  gemm256<2><<<dim3(512), B512, LDS256, stream>>>(Q2B, W1T, Hbuf, b1,
                                                  2048, 1024);
  gemm128<4><<<dim3(512), B512, LDS128, stream>>>(Hbuf, W2aT, out, nullptr,
                                                  1024, 2048);

  // FFN half B
  gemm256<2><<<dim3(512), B512, LDS256, stream>>>(Q2B, W1T + 2048 * 1024,
                                                  Hbuf, b1 + 2048, 2048,
                                                  1024);
  gemm128<4><<<dim3(512), B512, LDS128, stream>>>(Hbuf, W2bT, out, b2,
                                                  1024, 2048);

  // out = LN2(y) in-place
  ln_k<<<16384, B256, 0, stream>>>(out, nullptr, ln2g, ln2b, out, nullptr);
}

// Round 17
// 746.637 us; speedup vs baseline: 1.0688x; 1.0192x over previous
//
#include <hip/hip_runtime.h>

// Encoder block: LN1 -> QKV -> per-token head-mix attention -> scramble ->
// WO -> +x,LN1 -> W1+GELU (2 halves) -> W2 accum (+b2,+q2) -> LN2 in-place.
//
// FINAL (r17 == r16, measured best 761.0 us; session start was 918.3).
// Configuration history and rationale:
//  - gemm256 (single-phase, r8): 256x256 / BK=64 / 8 waves / 128 KiB LDS.
//    QKV (grid 768) + W1 halves (grid 512; >=2 rounds/CU regime).
//    Per K-tile: read all 24 frags -> 48 MFMA -> lgkm0 -> barrier ->
//    stage(u+2, 8 gloads) -> 16 reg-only MFMA -> vmcnt(8) counted ->
//    barrier. Measured 112 us / MfmaUtil 39% on QKV.
//  - gemm128 (ring-3, r9): 128x256 / BK=32 / 8 waves / 72 KiB LDS
//    (3 slots), ONE barrier/K-tile, (512,4) VGPR budget 128 (r5: (512,6)
//    spilled acc -> 2.4 GB scratch). WO + W2 halves (grid 512, 2 blk/CU).
//  - wconv_ln (r16): fused weight-convert (12288 blocks) + LN1(x) (16384
//    blocks) head launch — overlapped DRAM streams, -6..16 us.
//  - attn_k: LDS stride 65 (= 1 mod 32) kills the 16-way head-index bank
//    conflict (r7). Epilogues: per-wave LDS transpose + wide stores (r12).
//  - XCD mapping: bm-banded / bn-fastest (FETCH 135->49 MB, r3).
//  Falsified/abandoned: 8-phase per-phase interleave (r10: -12%),
//  gemm192 consolidations (r13/r14: cross-instantiation codegen lottery
//  +-30-60 us, rule #19), epilogue on critical path (r12: neutral).
//  Run-to-run noise: +-10 us (r15 byte-identical to r12: 777 vs 767).
// Workspace footprint: 152 MB (d_out doubles as the f32 residual buffer).

typedef __attribute__((ext_vector_type(8))) short s16x8;
typedef __attribute__((ext_vector_type(4))) short s16x4;
typedef __attribute__((ext_vector_type(4))) float f32x4;

__device__ __forceinline__ short f2bf(float x) {
  unsigned u = __builtin_bit_cast(unsigned, x);
  u = (u + 0x7FFFu + ((u >> 16) & 1u)) >> 16;
  return (short)u;
}
__device__ __forceinline__ float bf2f(short s) {
  unsigned u = ((unsigned)(unsigned short)s) << 16;
  return __builtin_bit_cast(float, u);
}

__device__ __forceinline__ void ld_g2l16(const short* g, const short* l) {
  __builtin_amdgcn_global_load_lds(
      (const __attribute__((address_space(1))) void*)g,
      (__attribute__((address_space(3))) void*)l, 16, 0, 0);
}

// Guaranteed-DS accesses: explicit addrspace(3) so codegen emits ds_* ops.
__device__ __forceinline__ s16x8 lds_read8(const short* smem, int off) {
  const __attribute__((address_space(3))) short* p =
      (const __attribute__((address_space(3))) short*)smem;
  return *(const __attribute__((address_space(3))) s16x8*)(p + off);
}
__device__ __forceinline__ void lds_wr_f32(const short* smem, int foff,
                                           float v) {
  __attribute__((address_space(3))) float* p =
      (__attribute__((address_space(3))) float*)smem;
  p[foff] = v;
}
__device__ __forceinline__ float lds_rd_f32(const short* smem, int foff) {
  const __attribute__((address_space(3))) float* p =
      (const __attribute__((address_space(3))) float*)smem;
  return p[foff];
}

// Fast GELU (tanh form via v_exp_f32; |err| ~1e-3 << bf16 noise).
__device__ __forceinline__ float fast_gelu(float v) {
  float y = 0.7978845608f * (v + 0.044715f * v * v * v);
  float ay = fabsf(y);
  float t = __expf(-2.0f * ay);
  float th = (1.0f - t) * __frcp_rn(1.0f + t);
  th = (y >= 0.f) ? th : -th;
  return 0.5f * v * (1.0f + th);
}

#define MFMA16(va, vb, vc) \
  __builtin_amdgcn_mfma_f32_16x16x32_bf16(va, vb, vc, 0, 0, 0)

// Shared vectorized epilogue body. Writes one 16-row chunk of a wave's
// 64-col tile. t-region: wave-private, f32 offset `two`, stride 17.
// EPI: 0 bf16; 1 f32; 2 +bias,GELU,bf16; 4 f32 accum (+bias).
template <int EPI>
__device__ __forceinline__ void epi_chunk(
    const short* smem, int two, int lane, const f32x4* accm /*[4]*/,
    void* __restrict__ outp, const float* __restrict__ bias, int N, int rowb,
    int nb) {
  const int cc16 = lane & 15, hq = lane >> 4;
#pragma unroll
  for (int n = 0; n < 4; ++n)
#pragma unroll
    for (int r = 0; r < 4; ++r)
      lds_wr_f32(smem, two + (n * 16 + cc16) * 17 + hq * 4 + r, accm[n][r]);
  asm volatile("s_waitcnt lgkmcnt(0)" ::: "memory");
  if constexpr (EPI == 0 || EPI == 2) {
    const int grp = lane & 7;
#pragma unroll
    for (int p = 0; p < 2; ++p) {
      const int row = p * 8 + (lane >> 3);
      const int colb = grp * 8;
      s16x8 ov;
#pragma unroll
      for (int i = 0; i < 8; ++i) {
        float v = lds_rd_f32(smem, two + (colb + i) * 17 + row);
        if constexpr (EPI == 2) v = fast_gelu(v + bias[nb + colb + i]);
        ov[i] = f2bf(v);
      }
      *(s16x8*)((short*)outp + (size_t)(rowb + row) * N + nb + colb) = ov;
    }
  } else {
    const int seg = lane & 3;
    const int row = lane >> 2;
#pragma unroll
    for (int k = 0; k < 4; ++k) {
      const int colb = seg * 4 + k * 16;
      float4 v4;
      v4.x = lds_rd_f32(smem, two + (colb + 0) * 17 + row);
      v4.y = lds_rd_f32(smem, two + (colb + 1) * 17 + row);
      v4.z = lds_rd_f32(smem, two + (colb + 2) * 17 + row);
      v4.w = lds_rd_f32(smem, two + (colb + 3) * 17 + row);
      float* gp = (float*)outp + (size_t)(rowb + row) * N + nb + colb;
      if constexpr (EPI == 4) {
        float4 pv = *(const float4*)gp;
        v4.x += pv.x; v4.y += pv.y; v4.z += pv.z; v4.w += pv.w;
        if (bias) {
          v4.x += bias[nb + colb + 0];
          v4.y += bias[nb + colb + 1];
          v4.z += bias[nb + colb + 2];
          v4.w += bias[nb + colb + 3];
        }
      }
      *(float4*)gp = v4;
    }
  }
  asm volatile("s_waitcnt lgkmcnt(0)" ::: "memory");
}

// ---------------------------------------------------------------------------
// gemm256: C[M,N] = A[M,K] @ BT[N,K]^T. M=16384. N,K multiples of 256.
// grid = 64*(N/256), 512 thr, dyn LDS 131072 B.  (r8 single-phase loop)
// ---------------------------------------------------------------------------
template <int EPI>
__global__ __launch_bounds__(512, 2) void gemm256(
    const short* __restrict__ A, const short* __restrict__ BT,
    void* __restrict__ outp, const float* __restrict__ bias, int N, int K) {
  extern __shared__ __align__(16) short smem[];

  const int t = threadIdx.x;
  const int lane = t & 63, w = t >> 6;
  const int wm = w >> 2, wn = w & 3;  // wave tile: rows wm*128, cols wn*64

  const int nbn = N >> 8;
  const int oi = (int)blockIdx.x;
  const int seq = oi >> 3;
  const int bq = seq / nbn;
  const int bm = (oi & 7) * 8 + bq;
  const int bn = seq - bq * nbn;

  const int l8 = lane >> 3;
  const int lcw = ((lane & 7) ^ l8) * 8;  // swizzled chunk offset (shorts)
  const short* gA = A + (size_t)(bm * 256 + w * 8 + l8) * K + lcw;
  const short* gB = BT + (size_t)(bn * 256 + w * 8 + l8) * K + lcw;
  const int lb = w * 512;

  auto stage = [&](const short* g, int bufo, int h, int kt) {
    const int go = h * 128 * K + kt * 64;
    ld_g2l16(g + go, smem + bufo + h * 8192 + lb);                  // q = 0
    ld_g2l16(g + go + 64 * K, smem + bufo + h * 8192 + 4096 + lb);  // q = 1
  };

  const int fr = lane & 15, fc = lane >> 4;
  const int baseA = (wm * 128 + fr) * 64;
  const int baseB = (wn * 64 + fr) * 64;
  const int sl0 = (fc ^ (fr & 7)) * 8;
  const int sl1 = ((4 + fc) ^ (fr & 7)) * 8;

  f32x4 acc[8][4];
#pragma unroll
  for (int m = 0; m < 8; ++m)
#pragma unroll
    for (int n = 0; n < 4; ++n) acc[m][n] = (f32x4){0.f, 0.f, 0.f, 0.f};

  const int nt = K >> 6;

  stage(gA, 0, 0, 0);
  stage(gA, 0, 1, 0);
  stage(gB, 32768, 0, 0);
  stage(gB, 32768, 1, 0);
  if (nt > 1) {
    stage(gA, 16384, 0, 1);
    stage(gA, 16384, 1, 1);
    stage(gB, 49152, 0, 1);
    stage(gB, 49152, 1, 1);
    asm volatile("s_waitcnt vmcnt(8)" ::: "memory");
  } else {
    asm volatile("s_waitcnt vmcnt(0)" ::: "memory");
  }
  __builtin_amdgcn_s_barrier();
  asm volatile("" ::: "memory");

  for (int u = 0; u < nt; ++u) {
    const bool pf = (u + 2 < nt);
    const int pa = (u & 1) << 14;
    const int pb = 32768 + pa;

    s16x8 a0[4][2], a1[4][2], b0[2][2], b1[2][2];
#pragma unroll
    for (int mi = 0; mi < 4; ++mi) {
      a0[mi][0] = lds_read8(smem, pa + baseA + mi * 1024 + sl0);
      a0[mi][1] = lds_read8(smem, pa + baseA + mi * 1024 + sl1);
    }
#pragma unroll
    for (int ni = 0; ni < 2; ++ni) {
      b0[ni][0] = lds_read8(smem, pb + baseB + ni * 1024 + sl0);
      b0[ni][1] = lds_read8(smem, pb + baseB + ni * 1024 + sl1);
    }
#pragma unroll
    for (int ni = 0; ni < 2; ++ni) {
      b1[ni][0] = lds_read8(smem, pb + baseB + 2048 + ni * 1024 + sl0);
      b1[ni][1] = lds_read8(smem, pb + baseB + 2048 + ni * 1024 + sl1);
    }
#pragma unroll
    for (int mi = 0; mi < 4; ++mi) {
      a1[mi][0] = lds_read8(smem, pa + baseA + 4096 + mi * 1024 + sl0);
      a1[mi][1] = lds_read8(smem, pa + baseA + 4096 + mi * 1024 + sl1);
    }

    __builtin_amdgcn_s_setprio(1);
#pragma unroll
    for (int mi = 0; mi < 4; ++mi)
#pragma unroll
      for (int ni = 0; ni < 2; ++ni) {
        acc[mi][ni] = MFMA16(a0[mi][0], b0[ni][0], acc[mi][ni]);
        acc[mi][ni] = MFMA16(a0[mi][1], b0[ni][1], acc[mi][ni]);
      }
#pragma unroll
    for (int mi = 0; mi < 4; ++mi)
#pragma unroll
      for (int ni = 0; ni < 2; ++ni) {
        acc[mi][2 + ni] = MFMA16(a0[mi][0], b1[ni][0], acc[mi][2 + ni]);
        acc[mi][2 + ni] = MFMA16(a0[mi][1], b1[ni][1], acc[mi][2 + ni]);
      }
#pragma unroll
    for (int mi = 0; mi < 4; ++mi)
#pragma unroll
      for (int ni = 0; ni < 2; ++ni) {
        acc[4 + mi][2 + ni] = MFMA16(a1[mi][0], b1[ni][0], acc[4 + mi][2 + ni]);
        acc[4 + mi][2 + ni] = MFMA16(a1[mi][1], b1[ni][1], acc[4 + mi][2 + ni]);
      }
    __builtin_amdgcn_s_setprio(0);

    asm volatile("s_waitcnt lgkmcnt(0)" ::: "memory");  // free (consumed)
    __builtin_amdgcn_s_barrier();
    asm volatile("" ::: "memory");

    if (pf) {
      stage(gB, pb, 0, u + 2);
      stage(gB, pb, 1, u + 2);
      stage(gA, pa, 0, u + 2);
      stage(gA, pa, 1, u + 2);
    }

    __builtin_amdgcn_s_setprio(1);
#pragma unroll
    for (int mi = 0; mi < 4; ++mi)
#pragma unroll
      for (int ni = 0; ni < 2; ++ni) {
        acc[4 + mi][ni] = MFMA16(a1[mi][0], b0[ni][0], acc[4 + mi][ni]);
        acc[4 + mi][ni] = MFMA16(a1[mi][1], b0[ni][1], acc[4 + mi][ni]);
      }
    __builtin_amdgcn_s_setprio(0);

    if (pf) {
      asm volatile("s_waitcnt vmcnt(8)" ::: "memory");
    } else {
      asm volatile("s_waitcnt vmcnt(0)" ::: "memory");
    }
    __builtin_amdgcn_s_barrier();
    asm volatile("" ::: "memory");
  }

  // Vectorized epilogue (wave-private LDS transpose; LDS free after loop).
  const int two = w * 1088;  // f32 offset of wave region (4352 B each)
  const int mb = bm * 256 + wm * 128;
  const int nb = bn * 256 + wn * 64;
#pragma unroll
  for (int m = 0; m < 8; ++m)
    epi_chunk<EPI>(smem, two, lane, acc[m], outp, bias, N, mb + m * 16, nb);
}

// ---------------------------------------------------------------------------
// gemm128 RING-3: tile 128x256, BK=32, 8 waves (2Mx4N, wave 64x64).
// LDS = 3 parity slots x 24 KB = 73728 B. ONE barrier + one counted vmcnt
// per K-tile. __launch_bounds__(512,4): 2 blocks/CU. grid = 128*(N/256).
// ---------------------------------------------------------------------------
template <int EPI>
__global__ __launch_bounds__(512, 4) void gemm128(
    const short* __restrict__ A, const short* __restrict__ BT,
    void* __restrict__ outp, const float* __restrict__ bias, int N, int K) {
  extern __shared__ __align__(16) short smem[];

  const int t = threadIdx.x;
  const int lane = t & 63, w = t >> 6;
  const int wm = w >> 2, wn = w & 3;  // wave tile: rows wm*64, cols wn*64

  // bm-banded / bn-fastest XCD mapping; nbm = 128 (M = 16384).
  const int nbn = N >> 8;
  const int oi = (int)blockIdx.x;
  const int seq = oi >> 3;
  const int bq = seq / nbn;
  const int bm = (oi & 7) * 16 + bq;
  const int bn = seq - bq * nbn;

  // Staging: lane -> (row = lane>>2, LDS slot = lane&3); global chunk
  // pre-rotated: c = ((lane&3) - ((lane>>3)&3)) & 3.
  const int lr = lane >> 2;
  const int lc = ((lane & 3) - ((lane >> 3) & 3)) & 3;
  const short* gA = A + (size_t)(bm * 128 + lr) * K + lc * 8;
  const short* gB = BT + (size_t)(bn * 256 + lr) * K + lc * 8;

  auto stageT = [&](int par, int kt) {
    ld_g2l16(gA + (size_t)(w * 16) * K + kt * 32, smem + par + w * 512);
    ld_g2l16(gB + (size_t)(2 * w * 16) * K + kt * 32,
             smem + par + 4096 + 2 * w * 512);
    ld_g2l16(gB + (size_t)((2 * w + 1) * 16) * K + kt * 32,
             smem + par + 4096 + (2 * w + 1) * 512);
  };

  const int fr = lane & 15, fc = lane >> 4;
  const int sl = ((fc + (fr >> 1)) & 3) * 8;
  const int baseA = (wm * 64 + fr) * 32 + sl;
  const int baseB = 4096 + (wn * 64 + fr) * 32 + sl;

  f32x4 acc[4][4];
#pragma unroll
  for (int m = 0; m < 4; ++m)
#pragma unroll
    for (int n = 0; n < 4; ++n) acc[m][n] = (f32x4){0.f, 0.f, 0.f, 0.f};

  const int nt = K >> 5;

  stageT(0, 0);
  stageT(12288, 1);
  asm volatile("s_waitcnt vmcnt(3)" ::: "memory");
  __builtin_amdgcn_s_barrier();
  asm volatile("" ::: "memory");

  int pcur = 0, pnxt = 12288, pprv = 24576;  // slots of u, u+1, u+2 (mod 3)
  for (int u = 0; u < nt; ++u) {
    const bool pf = (u + 2 < nt);

    if (pf) stageT(pprv, u + 2);

    s16x8 a[4], b[4];
#pragma unroll
    for (int i = 0; i < 4; ++i)
      a[i] = lds_read8(smem, pcur + baseA + i * 512);
#pragma unroll
    for (int i = 0; i < 4; ++i)
      b[i] = lds_read8(smem, pcur + baseB + i * 512);

    __builtin_amdgcn_s_setprio(1);
#pragma unroll
    for (int mi = 0; mi < 4; ++mi)
#pragma unroll
      for (int ni = 0; ni < 4; ++ni)
        acc[mi][ni] = MFMA16(a[mi], b[ni], acc[mi][ni]);
    __builtin_amdgcn_s_setprio(0);

    asm volatile("s_waitcnt lgkmcnt(0)" ::: "memory");  // reads retired
    if (pf) {
      asm volatile("s_waitcnt vmcnt(3)" ::: "memory");  // tile u+1 resident
    } else {
      asm volatile("s_waitcnt vmcnt(0)" ::: "memory");  // tail drain
    }
    __builtin_amdgcn_s_barrier();  // publishes tile u+1 for next iteration
    asm volatile("" ::: "memory");

    const int tmp = pcur;
    pcur = pnxt;
    pnxt = pprv;
    pprv = tmp;
  }

  // Vectorized epilogue (wave-private LDS transpose; LDS free after loop).
  const int two = w * 1088;
  const int mb = bm * 128 + wm * 64;
  const int nb = bn * 256 + wn * 64;
#pragma unroll
  for (int m = 0; m < 4; ++m)
    epi_chunk<EPI>(smem, two, lane, acc[m], outp, bias, N, mb + m * 16, nb);
}

// ---------------------------------------------------------------------------
// Row LayerNorm over D=1024. Optional fp32 `add` (residual). Writes fp32
// and/or bf16. One block (256 thr) per row. Safe in-place (outf == in).
// ---------------------------------------------------------------------------
__global__ __launch_bounds__(256) void ln_k(
    const float* __restrict__ in, const float* __restrict__ add,
    const float* __restrict__ g, const float* __restrict__ b,
    float* __restrict__ outf, short* __restrict__ outb) {
  const int row = blockIdx.x;
  const size_t off = (size_t)row * 1024;
  const int t = threadIdx.x;
  float4 v = ((const float4*)(in + off))[t];
  if (add) {
    float4 w = ((const float4*)(add + off))[t];
    v.x += w.x; v.y += w.y; v.z += w.z; v.w += w.w;
  }
  float s = v.x + v.y + v.z + v.w;
  float ss = v.x * v.x + v.y * v.y + v.z * v.z + v.w * v.w;
#pragma unroll
  for (int o = 32; o > 0; o >>= 1) {
    s += __shfl_xor(s, o, 64);
    ss += __shfl_xor(ss, o, 64);
  }
  __shared__ float ps[4], pss[4];
  const int lane = t & 63, wave = t >> 6;
  if (lane == 0) { ps[wave] = s; pss[wave] = ss; }
  __syncthreads();
  s = ps[0] + ps[1] + ps[2] + ps[3];
  ss = pss[0] + pss[1] + pss[2] + pss[3];
  const float mean = s * (1.0f / 1024.0f);
  const float var = ss * (1.0f / 1024.0f) - mean * mean;
  const float rstd = rsqrtf(var + 1e-6f);
  const float4 gv = ((const float4*)g)[t];
  const float4 bv = ((const float4*)b)[t];
  float4 o4;
  o4.x = (v.x - mean) * rstd * gv.x + bv.x;
  o4.y = (v.y - mean) * rstd * gv.y + bv.y;
  o4.z = (v.z - mean) * rstd * gv.z + bv.z;
  o4.w = (v.w - mean) * rstd * gv.w + bv.w;
  if (outf) ((float4*)(outf + off))[t] = o4;
  if (outb) {
    s16x4 ob;
    ob[0] = f2bf(o4.x); ob[1] = f2bf(o4.y);
    ob[2] = f2bf(o4.z); ob[3] = f2bf(o4.w);
    *(s16x4*)(outb + off + t * 4) = ob;
  }
}

// ---------------------------------------------------------------------------
// Fused head: weight convert+transpose (blocks 0..12287) AND LN1(x)->bf16
// (blocks 12288..28671, one row each). Independent memory-bound streams;
// fusing overlaps their DRAM traffic and removes one launch boundary.
// ---------------------------------------------------------------------------
__device__ __forceinline__ void wconv_tile(const float* __restrict__ W,
                                           short* __restrict__ WT, int K,
                                           int N, int n0, int k0,
                                           float (*tile)[33], int c, int r) {
#pragma unroll
  for (int rr = r; rr < 32; rr += 8)
    tile[rr][c] = W[(size_t)(k0 + rr) * N + n0 + c];
  __syncthreads();
#pragma unroll
  for (int rr = r; rr < 32; rr += 8)
    WT[(size_t)(n0 + rr) * K + k0 + c] = f2bf(tile[c][rr]);
}

__global__ __launch_bounds__(256) void wconv_ln(
    const float* __restrict__ wq, const float* __restrict__ wk,
    const float* __restrict__ wv, const float* __restrict__ wo,
    const float* __restrict__ w1, const float* __restrict__ w2,
    const float* __restrict__ x, const float* __restrict__ ln1g,
    const float* __restrict__ ln1b, short* __restrict__ WQKVT,
    short* __restrict__ WOT, short* __restrict__ W1T,
    short* __restrict__ W2aT, short* __restrict__ W2bT,
    short* __restrict__ X1) {
  __shared__ float tile[32][33];
  __shared__ float ps[4], pss[4];
  const int t = threadIdx.x;
  const int i = blockIdx.x;
  if (i < 12288) {  // ---- weight conversion path
    const int c = t & 31, r = t >> 5;
    if (i < 4096) {  // wq/wk/wv/wo: 1024x1024, 32x32 tiles each
      const int seg = i >> 10, j = i & 1023;
      const int n0 = (j & 31) * 32, k0 = (j >> 5) * 32;
      const float* src =
          (seg == 0) ? wq : (seg == 1) ? wk : (seg == 2) ? wv : wo;
      short* dst = (seg == 3) ? WOT : WQKVT + (size_t)seg * 1024 * 1024;
      wconv_tile(src, dst, 1024, 1024, n0, k0, tile, c, r);
    } else if (i < 8192) {  // w1: K=1024, N=4096
      const int j = i - 4096;
      const int n0 = (j & 127) * 32, k0 = (j >> 7) * 32;
      wconv_tile(w1, W1T, 1024, 4096, n0, k0, tile, c, r);
    } else if (i < 10240) {  // w2 rows 0-2047 -> W2aT
      const int j = i - 8192;
      const int n0 = (j & 31) * 32, k0 = (j >> 5) * 32;
      wconv_tile(w2, W2aT, 2048, 1024, n0, k0, tile, c, r);
    } else {  // w2 rows 2048-4095 -> W2bT
      const int j = i - 10240;
      const int n0 = (j & 31) * 32, k0 = (j >> 5) * 32;
      wconv_tile(w2 + (size_t)2048 * 1024, W2bT, 2048, 1024, n0, k0, tile, c,
                 r);
    }
  } else {  // ---- LN1(x) -> X1 bf16 path (one row per block)
    const int row = i - 12288;
    const size_t off = (size_t)row * 1024;
    float4 v = ((const float4*)(x + off))[t];
    float s = v.x + v.y + v.z + v.w;
    float ss = v.x * v.x + v.y * v.y + v.z * v.z + v.w * v.w;
#pragma unroll
    for (int o = 32; o > 0; o >>= 1) {
      s += __shfl_xor(s, o, 64);
      ss += __shfl_xor(ss, o, 64);
    }
    const int lane = t & 63, wave = t >> 6;
    if (lane == 0) { ps[wave] = s; pss[wave] = ss; }
    __syncthreads();
    s = ps[0] + ps[1] + ps[2] + ps[3];
    ss = pss[0] + pss[1] + pss[2] + pss[3];
    const float mean = s * (1.0f / 1024.0f);
    const float var = ss * (1.0f / 1024.0f) - mean * mean;
    const float rstd = rsqrtf(var + 1e-6f);
    const float4 gv = ((const float4*)ln1g)[t];
    const float4 bv = ((const float4*)ln1b)[t];
    s16x4 ob;
    ob[0] = f2bf((v.x - mean) * rstd * gv.x + bv.x);
    ob[1] = f2bf((v.y - mean) * rstd * gv.y + bv.y);
    ob[2] = f2bf((v.z - mean) * rstd * gv.z + bv.z);
    ob[3] = f2bf((v.w - mean) * rstd * gv.w + bv.w);
    *(s16x4*)(X1 + off + t * 4) = ob;
  }
}

// ---------------------------------------------------------------------------
// Per-token head-mixing attention + faithful-reshape scramble.
// LDS rows padded: stride 65 (= 1 mod 32). Ps stride 17.
// ---------------------------------------------------------------------------
__global__ __launch_bounds__(256) void attn_k(const short* __restrict__ qkv,
                                              short* __restrict__ omix) {
  __shared__ float Qs[4][16][65];
  __shared__ float Ks[4][16][65];
  __shared__ float Vs[4][16][65];
  __shared__ float Ps[4][16][17];
  const int lane = threadIdx.x & 63;
  const int wave = threadIdx.x >> 6;
  const int tok = blockIdx.x * 4 + wave;
  const short* base = qkv + (size_t)tok * 3072;

#pragma unroll
  for (int half = 0; half < 2; half++) {
    const int e = half * 512 + lane * 8;
    const int h = e >> 6, d = e & 63;
    s16x8 rq = *(const s16x8*)(base + e);
    s16x8 rk = *(const s16x8*)(base + 1024 + e);
    s16x8 rv = *(const s16x8*)(base + 2048 + e);
#pragma unroll
    for (int j = 0; j < 8; j++) {
      Qs[wave][h][d + j] = bf2f(rq[j]);
      Ks[wave][h][d + j] = bf2f(rk[j]);
      Vs[wave][h][d + j] = bf2f(rv[j]);
    }
  }
  __syncthreads();

  const int h = lane & 15;
  const int g0 = (lane >> 4) * 4;
  float sc[4] = {0.f, 0.f, 0.f, 0.f};
  for (int d = 0; d < 64; d++) {
    const float qv = Qs[wave][h][d];
#pragma unroll
    for (int i = 0; i < 4; i++) sc[i] += qv * Ks[wave][g0 + i][d];
  }
#pragma unroll
  for (int i = 0; i < 4; i++) sc[i] *= 0.125f;
  float m = fmaxf(fmaxf(sc[0], sc[1]), fmaxf(sc[2], sc[3]));
  m = fmaxf(m, __shfl_xor(m, 16, 64));
  m = fmaxf(m, __shfl_xor(m, 32, 64));
  float e[4], sum = 0.f;
#pragma unroll
  for (int i = 0; i < 4; i++) { e[i] = __expf(sc[i] - m); sum += e[i]; }
  sum += __shfl_xor(sum, 16, 64);
  sum += __shfl_xor(sum, 32, 64);
  const float inv = __frcp_rn(sum);
#pragma unroll
  for (int i = 0; i < 4; i++) Ps[wave][h][g0 + i] = e[i] * inv;
  __syncthreads();

  const int d0 = (lane >> 4) * 16;
  float o[16];
#pragma unroll
  for (int dd = 0; dd < 16; dd++) o[dd] = 0.f;
  for (int gg = 0; gg < 16; gg++) {
    const float pv = Ps[wave][h][gg];
#pragma unroll
    for (int dd = 0; dd < 16; dd++) o[dd] += pv * Vs[wave][gg][d0 + dd];
  }

  const int b = tok >> 12, t = tok & 4095;
  const size_t dst =
      ((size_t)(b * 4096 + h * 256 + (t >> 4))) * 1024 + (t & 15) * 64 + d0;
  s16x8 w0, w1;
#pragma unroll
  for (int j = 0; j < 8; j++) { w0[j] = f2bf(o[j]); w1[j] = f2bf(o[8 + j]); }
  *(s16x8*)(omix + dst) = w0;
  *(s16x8*)(omix + dst + 8) = w1;
}

// ---------------------------------------------------------------------------
extern "C" void kernel_launch(void* const* d_in, const int* in_sizes, int n_in,
                              void* d_out, int out_size, void* d_ws,
                              size_t ws_size, hipStream_t stream) {
  const float* x    = (const float*)d_in[0];
  const float* wq   = (const float*)d_in[1];
  const float* wk   = (const float*)d_in[2];
  const float* wv   = (const float*)d_in[3];
  const float* wo   = (const float*)d_in[4];
  const float* ln1g = (const float*)d_in[5];
  const float* ln1b = (const float*)d_in[6];
  const float* w1   = (const float*)d_in[7];
  const float* b1   = (const float*)d_in[8];
  const float* w2   = (const float*)d_in[9];
  const float* b2   = (const float*)d_in[10];
  const float* ln2g = (const float*)d_in[11];
  const float* ln2b = (const float*)d_in[12];
  float* out = (float*)d_out;  // [16384,1024] f32; doubles as o2/q2 buffer

  char* ws = (char*)d_ws;
  const size_t MB = 1024ull * 1024ull;
  const size_t NEEDED = 152 * MB;
  if (ws_size < NEEDED) return;  // fail-numeric instead of page-fault

  short* QKV  = (short*)(ws + 0);        // phase1 [16384,3072] bf16
  short* Q2B  = (short*)(ws + 0);        // phase2 [16384,1024] bf16
  short* Hbuf = (short*)(ws + 32 * MB);  // phase2 [16384,2048] bf16
  short* X1 = (short*)(ws + 96 * MB);    // x1, then o_mixed bf16
  short* WQKVT = (short*)(ws + 128 * MB);
  short* WOT   = (short*)(ws + 134 * MB);
  short* W1T   = (short*)(ws + 136 * MB);
  short* W2aT  = (short*)(ws + 144 * MB);
  short* W2bT  = (short*)(ws + 148 * MB);

  const dim3 B256(256);
  const dim3 B512(512);
  const unsigned LDS256 = 131072;  // gemm256
  const unsigned LDS128 = 73728;   // gemm128 ring-3

  static bool attr_done = false;
  if (!attr_done) {
    attr_done = true;
    void (*k0)(const short*, const short*, void*, const float*, int, int) =
        gemm256<0>;
    void (*k2)(const short*, const short*, void*, const float*, int, int) =
        gemm256<2>;
    (void)hipFuncSetAttribute((const void*)k0,
        hipFuncAttributeMaxDynamicSharedMemorySize, (int)LDS256);
    (void)hipFuncSetAttribute((const void*)k2,
        hipFuncAttributeMaxDynamicSharedMemorySize, (int)LDS256);
    void (*h1)(const short*, const short*, void*, const float*, int, int) =
        gemm128<1>;
    void (*h4)(const short*, const short*, void*, const float*, int, int) =
        gemm128<4>;
    (void)hipFuncSetAttribute((const void*)h1,
        hipFuncAttributeMaxDynamicSharedMemorySize, (int)LDS128);
    (void)hipFuncSetAttribute((const void*)h4,
        hipFuncAttributeMaxDynamicSharedMemorySize, (int)LDS128);
  }

  // Fused head: all weight conversions + LN1(x)->X1 in ONE launch.
  wconv_ln<<<dim3(28672), B256, 0, stream>>>(wq, wk, wv, wo, w1, w2, x, ln1g,
                                             ln1b, WQKVT, WOT, W1T, W2aT,
                                             W2bT, X1);

  // QKV = x1 @ [wq|wk|wv]   (gemm256 single-phase, grid 768)
  gemm256<0><<<dim3(768), B512, LDS256, stream>>>(X1, WQKVT, QKV, nullptr,
                                                  3072, 1024);

  // attention + scramble -> o_mixed (reuses X1 region)
  attn_k<<<4096, B256, 0, stream>>>(QKV, X1);

  // o2 = o_mixed @ wo -> f32 into d_out   (gemm128 ring-3: grid 512)
  gemm128<1><<<dim3(512), B512, LDS128, stream>>>(X1, WOT, out, nullptr,
                                                  1024, 1024);

  // q2 = LN1(o2 + x): f32 in-place in d_out, bf16 copy in Q2B
  ln_k<<<16384, B256, 0, stream>>>(out, x, ln1g, ln1b, out, Q2B);

  // FFN half A  (W1: gemm256 grid 512 = 2 rounds/CU; W2: gemm128 grid 512)
  gemm256<2><<<dim3(512), B512, LDS256, stream>>>(Q2B, W1T, Hbuf, b1,
                                                  2048, 1024);
  gemm128<4><<<dim3(512), B512, LDS128, stream>>>(Hbuf, W2aT, out, nullptr,
                                                  1024, 2048);

  // FFN half B
  gemm256<2><<<dim3(512), B512, LDS256, stream>>>(Q2B, W1T + 2048 * 1024,
                                                  Hbuf, b1 + 2048, 2048,
                                                  1024);
  gemm128<4><<<dim3(512), B512, LDS128, stream>>>(Hbuf, W2bT, out, b2,
                                                  1024, 2048);

  // out = LN2(y) in-place
  ln_k<<<16384, B256, 0, stream>>>(out, nullptr, ln2g, ln2b, out, nullptr);
}